// Round 1
// baseline (3424.053 us; speedup 1.0000x reference)
//
#include <hip/hip_runtime.h>

// Frag2Mol: embed -> encoder(VAE) -> 2x GRU(scan over T=64) -> vocab GEMM.
// Sizes: B=32 S=64 V=32000 E=128 H=512 L=2 LAT=64.
// Strategy r1: bf16 MFMA for all GEMMs; f32 recurrence, 1 WG/batch scan.

typedef __attribute__((ext_vector_type(8))) short bf16x8_t;          // 8 bf16 (4 VGPR)
typedef __attribute__((ext_vector_type(8))) unsigned short u16x8_t;  // 16B
typedef __attribute__((ext_vector_type(4))) float f32x4_t;           // MFMA acc

static __device__ __forceinline__ unsigned short f2bf(float f) {
    unsigned int u = __float_as_uint(f);
    u += 0x7fffu + ((u >> 16) & 1u);   // round-to-nearest-even
    return (unsigned short)(u >> 16);
}

// ---------------- f32 -> bf16 convert (n multiple of 4) ----------------
__global__ __launch_bounds__(256) void cvt_bf16_kernel(const float* __restrict__ in,
                                                       unsigned short* __restrict__ out, int n4) {
    int stride = gridDim.x * 256;
    for (int i = blockIdx.x * 256 + threadIdx.x; i < n4; i += stride) {
        float4 v = reinterpret_cast<const float4*>(in)[i];
        ushort4 o;
        o.x = f2bf(v.x); o.y = f2bf(v.y); o.z = f2bf(v.z); o.w = f2bf(v.w);
        reinterpret_cast<ushort4*>(out)[i] = o;
    }
}

// ---------------- transpose RxC f32 -> CxR (R,C multiples of 32) ----------------
__global__ __launch_bounds__(256) void transpose_kernel(const float* __restrict__ in,
                                                        float* __restrict__ out, int R, int C) {
    __shared__ float tile[32][33];
    int c0 = blockIdx.x * 32, r0 = blockIdx.y * 32;
    int tx = threadIdx.x & 31, ty = threadIdx.x >> 5;  // ty 0..7
#pragma unroll
    for (int i = 0; i < 32; i += 8) tile[ty + i][tx] = in[(size_t)(r0 + ty + i) * C + c0 + tx];
    __syncthreads();
#pragma unroll
    for (int i = 0; i < 32; i += 8) out[(size_t)(c0 + ty + i) * R + r0 + tx] = tile[tx][ty + i];
}

// ---------------- embedding + masked sum ----------------
__global__ __launch_bounds__(128) void embed_kernel(const int* __restrict__ tok,
                                                    const float* __restrict__ table,
                                                    unsigned short* __restrict__ embb,  // 2048x128 bf16
                                                    float* __restrict__ vf) {           // 32x128
    const int b = blockIdx.x, e = threadIdx.x;
    float acc = 0.f;
    for (int s = 0; s < 64; ++s) {
        int id = tok[b * 64 + s];
        float v = table[(size_t)id * 128 + e];
        embb[(size_t)(b * 64 + s) * 128 + e] = f2bf(v);
        if (id > 2) acc += v;
    }
    vf[b * 128 + e] = acc;
}

// ---------------- encoder: mean/std/z, state = z@Wl2r^T, 2 MLPs ----------------
__global__ __launch_bounds__(256) void encoder_kernel(
    const float* __restrict__ vf,                                        // 32x128
    const float* __restrict__ Wm, const float* __restrict__ bm,          // 64x128, 64
    const float* __restrict__ Wv, const float* __restrict__ bv,
    const float* __restrict__ noise,                                     // 2x32x64
    const float* __restrict__ Wl2r, const float* __restrict__ bl2r,      // 512x64, 512
    const float* __restrict__ lW1, const float* __restrict__ lb1,
    const float* __restrict__ lW2, const float* __restrict__ lb2,
    const float* __restrict__ lW3, const float* __restrict__ lb3,
    const float* __restrict__ sW1, const float* __restrict__ sb1,
    const float* __restrict__ sW2, const float* __restrict__ sb2,
    const float* __restrict__ sW3, const float* __restrict__ sb3,
    float* __restrict__ o_mean, float* __restrict__ o_std, float* __restrict__ o_z,
    float* __restrict__ o_logp, float* __restrict__ o_sas,
    float* __restrict__ state)                                           // 2x32x512
{
    const int b = blockIdx.x, tid = threadIdx.x;
    __shared__ float v_[128], mn[64], sd[64], zz[2][64], hh1[200], hh2[100];
    if (tid < 128) v_[tid] = vf[b * 128 + tid];
    __syncthreads();
    if (tid < 128) {
        int j = tid & 63;
        bool isv = tid >= 64;
        const float* W = (isv ? Wv : Wm) + j * 128;
        float a = isv ? bv[j] : bm[j];
#pragma unroll 4
        for (int k = 0; k < 128; ++k) a = fmaf(v_[k], W[k], a);
        if (!isv) { mn[j] = a; o_mean[b * 64 + j] = a; }
        else      { float s = __expf(0.5f * a); sd[j] = s; o_std[b * 64 + j] = s; }
    }
    __syncthreads();
    if (tid < 128) {
        int l = tid >> 6, j = tid & 63;
        float zv = fmaf(noise[(l * 32 + b) * 64 + j], sd[j], mn[j]);
        zz[l][j] = zv;
        o_z[(l * 32 + b) * 64 + j] = zv;
    }
    __syncthreads();
#pragma unroll
    for (int p = 0; p < 4; ++p) {   // state: 2x512 rows, K=64
        int tt = p * 256 + tid;
        int l = tt >> 9, hd = tt & 511;
        const float* W = Wl2r + hd * 64;
        float a = bl2r[hd];
#pragma unroll 4
        for (int k = 0; k < 64; ++k) a = fmaf(zz[l][k], W[k], a);
        state[(size_t)(l * 32 + b) * 512 + hd] = a;
    }
    // logp MLP
    if (tid < 200) {
        const float* W = lW1 + tid * 64;
        float a = lb1[tid];
        for (int k = 0; k < 64; ++k) a = fmaf(mn[k], W[k], a);
        hh1[tid] = fmaxf(a, 0.f);
    }
    __syncthreads();
    if (tid < 100) {
        const float* W = lW2 + tid * 200;
        float a = lb2[tid];
        for (int k = 0; k < 200; ++k) a = fmaf(hh1[k], W[k], a);
        hh2[tid] = fmaxf(a, 0.f);
    }
    __syncthreads();
    if (tid == 0) {
        float a = lb3[0];
        for (int k = 0; k < 100; ++k) a = fmaf(hh2[k], lW3[k], a);
        o_logp[b] = a;
    }
    __syncthreads();
    // sas MLP (reuse hh1/hh2)
    if (tid < 200) {
        const float* W = sW1 + tid * 64;
        float a = sb1[tid];
        for (int k = 0; k < 64; ++k) a = fmaf(mn[k], W[k], a);
        hh1[tid] = fmaxf(a, 0.f);
    }
    __syncthreads();
    if (tid < 100) {
        const float* W = sW2 + tid * 200;
        float a = sb2[tid];
        for (int k = 0; k < 200; ++k) a = fmaf(hh1[k], W[k], a);
        hh2[tid] = fmaxf(a, 0.f);
    }
    __syncthreads();
    if (tid == 0) {
        float a = sb3[0];
        for (int k = 0; k < 100; ++k) a = fmaf(hh2[k], sW3[k], a);
        o_sas[b] = a;
    }
}

// ---------------- bf16 MFMA GEMM: C(MxN,f32) = A(MxK) * B(NxK)^T + bias ----------------
// 128x128 tile, BK=64, 4 waves (2x2 quadrants of 64x64), reg-staged LDS, XOR swizzle.
// M%128==0, N%128==0, K%64==0 (all shapes here satisfy this).
__global__ __launch_bounds__(256) void gemm_bt_kernel(
    const unsigned short* __restrict__ A,  // M x K bf16 row-major
    const unsigned short* __restrict__ B,  // N x K bf16 row-major (i.e. B^T input)
    const float* __restrict__ bias,        // N (may be null)
    float* __restrict__ C,                 // M x N f32
    int M, int N, int K)
{
    __shared__ unsigned short lA[128 * 64];  // 16 KB, XOR-swizzled granules
    __shared__ unsigned short lB[128 * 64];
    const int tid = threadIdx.x;
    const int lane = tid & 63;
    const int wave = tid >> 6;
    const int wm = wave >> 1, wn = wave & 1;
    const int m0 = blockIdx.y * 128, n0 = blockIdx.x * 128;

    f32x4_t acc[4][4];
#pragma unroll
    for (int i = 0; i < 4; ++i)
#pragma unroll
        for (int j = 0; j < 4; ++j) acc[i][j] = (f32x4_t){0.f, 0.f, 0.f, 0.f};

    for (int kt = 0; kt < K; kt += 64) {
        // stage: 1024 granules (16B) per tile; swizzle: granule (row, c^ (row&7))
#pragma unroll
        for (int p = 0; p < 4; ++p) {
            int g = p * 256 + tid;
            int row = g >> 3, c8 = g & 7;
            int dst = row * 64 + ((c8 ^ (row & 7)) << 3);
            *(u16x8_t*)&lA[dst] = *(const u16x8_t*)(A + (size_t)(m0 + row) * K + kt + (c8 << 3));
            *(u16x8_t*)&lB[dst] = *(const u16x8_t*)(B + (size_t)(n0 + row) * K + kt + (c8 << 3));
        }
        __syncthreads();
#pragma unroll
        for (int kc = 0; kc < 2; ++kc) {
            bf16x8_t af[4], bfr[4];
            int c8 = kc * 4 + (lane >> 4);
#pragma unroll
            for (int i = 0; i < 4; ++i) {
                int ra = wm * 64 + i * 16 + (lane & 15);
                af[i] = *(const bf16x8_t*)&lA[ra * 64 + ((c8 ^ (ra & 7)) << 3)];
                int rb = wn * 64 + i * 16 + (lane & 15);
                bfr[i] = *(const bf16x8_t*)&lB[rb * 64 + ((c8 ^ (rb & 7)) << 3)];
            }
#pragma unroll
            for (int i = 0; i < 4; ++i)
#pragma unroll
                for (int j = 0; j < 4; ++j)
                    acc[i][j] = __builtin_amdgcn_mfma_f32_16x16x32_bf16(af[i], bfr[j], acc[i][j], 0, 0, 0);
        }
        __syncthreads();
    }
    // epilogue: C/D layout col = lane&15 (N), row = (lane>>4)*4 + reg (M)
    const int lm = (lane >> 4) * 4, ln = lane & 15;
#pragma unroll
    for (int i = 0; i < 4; ++i) {
        int gm = m0 + wm * 64 + i * 16 + lm;
#pragma unroll
        for (int j = 0; j < 4; ++j) {
            int gn = n0 + wn * 64 + j * 16 + ln;
            float bb = bias ? bias[gn] : 0.f;
#pragma unroll
            for (int r = 0; r < 4; ++r)
                C[(size_t)(gm + r) * N + gn] = acc[i][j][r] + bb;
        }
    }
}

// ---------------- GRU scan: 1 WG per batch, 512 thr, thread d owns h-dim d ----------------
__global__ __launch_bounds__(512) void gru_scan_kernel(
    const float* __restrict__ xW,    // 2048 x 1536 (x@Wih^T + bih), row = b*64+t
    const float* __restrict__ WhhT,  // 512 x 1536 (Whh transposed)
    const float* __restrict__ bhh,   // 1536
    const float* __restrict__ h0,    // 32 x 512 (this layer's init state)
    const int* __restrict__ lengths,
    unsigned short* __restrict__ outb)  // 2048 x 512 bf16 (masked: zeros)
{
    const int b = blockIdx.x;
    const int d = threadIdx.x;  // 0..511
    __shared__ float h[512];
    h[d] = h0[b * 512 + d];
    __syncthreads();
    const int len = lengths[b];
    const float bh_r = bhh[d], bh_z = bhh[512 + d], bh_n = bhh[1024 + d];
    for (int t = 0; t < 64; ++t) {
        if (t >= len) {  // uniform across block
            for (int tt = t; tt < 64; ++tt) outb[(size_t)(b * 64 + tt) * 512 + d] = 0;
            break;
        }
        float ar = 0.f, az = 0.f, an = 0.f;
#pragma unroll 4
        for (int k = 0; k < 512; ++k) {
            float hk = h[k];  // LDS broadcast
            const float* w = WhhT + k * 1536 + d;  // coalesced across threads
            ar = fmaf(hk, w[0], ar);
            az = fmaf(hk, w[512], az);
            an = fmaf(hk, w[1024], an);
        }
        __syncthreads();  // all reads of h done before update
        const float* xr_ = xW + (size_t)(b * 64 + t) * 1536;
        float xr = xr_[d], xz = xr_[512 + d], xn = xr_[1024 + d];
        float r = 1.f / (1.f + __expf(-(xr + ar + bh_r)));
        float u = 1.f / (1.f + __expf(-(xz + az + bh_z)));
        float n = tanhf(xn + r * (an + bh_n));
        float hnew = (1.f - u) * n + u * h[d];
        h[d] = hnew;
        outb[(size_t)(b * 64 + t) * 512 + d] = f2bf(hnew);
        __syncthreads();  // h visible before next step's dots
    }
}

extern "C" void kernel_launch(void* const* d_in, const int* in_sizes, int n_in,
                              void* d_out, int out_size, void* d_ws, size_t ws_size,
                              hipStream_t stream) {
    const int*   tok    = (const int*)d_in[0];
    const int*   lens   = (const int*)d_in[1];
    const float* noise  = (const float*)d_in[2];
    const float* table  = (const float*)d_in[3];
    const float* Wm     = (const float*)d_in[4];
    const float* bm_    = (const float*)d_in[5];
    const float* Wv     = (const float*)d_in[6];
    const float* bv_    = (const float*)d_in[7];
    const float* Wl2r   = (const float*)d_in[8];
    const float* bl2r   = (const float*)d_in[9];
    const float* Wih0   = (const float*)d_in[10];
    const float* Whh0   = (const float*)d_in[11];
    const float* bih0   = (const float*)d_in[12];
    const float* bhh0   = (const float*)d_in[13];
    const float* Wih1   = (const float*)d_in[14];
    const float* Whh1   = (const float*)d_in[15];
    const float* bih1   = (const float*)d_in[16];
    const float* bhh1   = (const float*)d_in[17];
    const float* Wout   = (const float*)d_in[18];
    const float* bout   = (const float*)d_in[19];
    const float* lW1 = (const float*)d_in[20]; const float* lb1 = (const float*)d_in[21];
    const float* lW2 = (const float*)d_in[22]; const float* lb2 = (const float*)d_in[23];
    const float* lW3 = (const float*)d_in[24]; const float* lb3 = (const float*)d_in[25];
    const float* sW1 = (const float*)d_in[26]; const float* sb1 = (const float*)d_in[27];
    const float* sW2 = (const float*)d_in[28]; const float* sb2 = (const float*)d_in[29];
    const float* sW3 = (const float*)d_in[30]; const float* sb3 = (const float*)d_in[31];

    float* out    = (float*)d_out;           // (B,S,V) = 2048 x 32000
    float* o_mean = out + 65536000;          // (32,64)
    float* o_std  = o_mean + 2048;
    float* o_z    = o_std + 2048;            // (2,32,64)
    float* o_logp = o_z + 4096;              // (32,)
    float* o_sas  = o_logp + 32;

    char* ws = (char*)d_ws;
    unsigned short* Woutb = (unsigned short*)ws;  ws += 32768000;  // 32000x512 bf16
    unsigned short* Wih0b = (unsigned short*)ws;  ws += 393216;    // 1536x128 bf16
    unsigned short* Wih1b = (unsigned short*)ws;  ws += 1572864;   // 1536x512 bf16
    float*          WhhT0 = (float*)ws;           ws += 3145728;   // 512x1536 f32
    float*          WhhT1 = (float*)ws;           ws += 3145728;
    unsigned short* embb  = (unsigned short*)ws;  ws += 524288;    // 2048x128 bf16
    float*          vf    = (float*)ws;           ws += 16384;     // 32x128
    float*          state = (float*)ws;           ws += 131072;    // 2x32x512
    float*          xW    = (float*)ws;           ws += 12582912;  // 2048x1536 f32 (reused)
    unsigned short* out0b = (unsigned short*)ws;  ws += 2097152;   // 2048x512 bf16
    unsigned short* out1b = (unsigned short*)ws;  ws += 2097152;

    // weight preprocessing (input-independent)
    cvt_bf16_kernel<<<dim3(4096), dim3(256), 0, stream>>>(Wout, Woutb, 16384000 / 4);
    cvt_bf16_kernel<<<dim3(192),  dim3(256), 0, stream>>>(Wih0, Wih0b, 196608 / 4);
    cvt_bf16_kernel<<<dim3(768),  dim3(256), 0, stream>>>(Wih1, Wih1b, 786432 / 4);
    transpose_kernel<<<dim3(16, 48), dim3(256), 0, stream>>>(Whh0, WhhT0, 1536, 512);
    transpose_kernel<<<dim3(16, 48), dim3(256), 0, stream>>>(Whh1, WhhT1, 1536, 512);

    // encoder path
    embed_kernel<<<dim3(32), dim3(128), 0, stream>>>(tok, table, embb, vf);
    encoder_kernel<<<dim3(32), dim3(256), 0, stream>>>(vf, Wm, bm_, Wv, bv_, noise, Wl2r, bl2r,
                                                       lW1, lb1, lW2, lb2, lW3, lb3,
                                                       sW1, sb1, sW2, sb2, sW3, sb3,
                                                       o_mean, o_std, o_z, o_logp, o_sas, state);

    // GRU layer 0
    gemm_bt_kernel<<<dim3(12, 16), dim3(256), 0, stream>>>(embb, Wih0b, bih0, xW, 2048, 1536, 128);
    gru_scan_kernel<<<dim3(32), dim3(512), 0, stream>>>(xW, WhhT0, bhh0, state, lens, out0b);
    // GRU layer 1
    gemm_bt_kernel<<<dim3(12, 16), dim3(256), 0, stream>>>(out0b, Wih1b, bih1, xW, 2048, 1536, 512);
    gru_scan_kernel<<<dim3(32), dim3(512), 0, stream>>>(xW, WhhT1, bhh1, state + 32 * 512, lens, out1b);

    // output projection (B,S,V)
    gemm_bt_kernel<<<dim3(250, 16), dim3(256), 0, stream>>>(out1b, Woutb, bout, out, 2048, 32000, 512);
}

// Round 2
// 1354.622 us; speedup vs baseline: 2.5277x; 2.5277x over previous
//
#include <hip/hip_runtime.h>

// Frag2Mol: embed -> encoder(VAE) -> 2x GRU(scan over T=64) -> vocab GEMM.
// Sizes: B=32 S=64 V=32000 E=128 H=512 L=2 LAT=64.
// r2: GRU scan -> cooperative-style MFMA kernel (64 WGs, Whh in LDS as f16
//     fragments, per-step device barrier). Old per-batch scan was 1.45%
//     occupancy latency-bound (2x1616us).

typedef __attribute__((ext_vector_type(8))) short bf16x8_t;          // 8 bf16 (4 VGPR)
typedef __attribute__((ext_vector_type(8))) unsigned short u16x8_t;  // 16B
typedef __attribute__((ext_vector_type(4))) float f32x4_t;           // MFMA acc
typedef __attribute__((ext_vector_type(8))) _Float16 f16x8_t;        // 8 f16

static __device__ __forceinline__ unsigned short f2bf(float f) {
    unsigned int u = __float_as_uint(f);
    u += 0x7fffu + ((u >> 16) & 1u);   // round-to-nearest-even
    return (unsigned short)(u >> 16);
}
static __device__ __forceinline__ unsigned short f2h(float f) {
    _Float16 h = (_Float16)f;
    return __builtin_bit_cast(unsigned short, h);
}
static __device__ __forceinline__ float sigmoidf_(float x) {
    return 1.f / (1.f + __expf(-x));
}

// ---------------- f32 -> bf16 convert (n multiple of 4) ----------------
__global__ __launch_bounds__(256) void cvt_bf16_kernel(const float* __restrict__ in,
                                                       unsigned short* __restrict__ out, int n4) {
    int stride = gridDim.x * 256;
    for (int i = blockIdx.x * 256 + threadIdx.x; i < n4; i += stride) {
        float4 v = reinterpret_cast<const float4*>(in)[i];
        ushort4 o;
        o.x = f2bf(v.x); o.y = f2bf(v.y); o.z = f2bf(v.z); o.w = f2bf(v.w);
        reinterpret_cast<ushort4*>(out)[i] = o;
    }
}

// ---------------- embedding + masked sum ----------------
__global__ __launch_bounds__(128) void embed_kernel(const int* __restrict__ tok,
                                                    const float* __restrict__ table,
                                                    unsigned short* __restrict__ embb,  // 2048x128 bf16
                                                    float* __restrict__ vf) {           // 32x128
    const int b = blockIdx.x, e = threadIdx.x;
    float acc = 0.f;
    for (int s = 0; s < 64; ++s) {
        int id = tok[b * 64 + s];
        float v = table[(size_t)id * 128 + e];
        embb[(size_t)(b * 64 + s) * 128 + e] = f2bf(v);
        if (id > 2) acc += v;
    }
    vf[b * 128 + e] = acc;
}

// ---------------- encoder: mean/std/z, state = z@Wl2r^T, 2 MLPs ----------------
__global__ __launch_bounds__(256) void encoder_kernel(
    const float* __restrict__ vf,
    const float* __restrict__ Wm, const float* __restrict__ bm,
    const float* __restrict__ Wv, const float* __restrict__ bv,
    const float* __restrict__ noise,
    const float* __restrict__ Wl2r, const float* __restrict__ bl2r,
    const float* __restrict__ lW1, const float* __restrict__ lb1,
    const float* __restrict__ lW2, const float* __restrict__ lb2,
    const float* __restrict__ lW3, const float* __restrict__ lb3,
    const float* __restrict__ sW1, const float* __restrict__ sb1,
    const float* __restrict__ sW2, const float* __restrict__ sb2,
    const float* __restrict__ sW3, const float* __restrict__ sb3,
    float* __restrict__ o_mean, float* __restrict__ o_std, float* __restrict__ o_z,
    float* __restrict__ o_logp, float* __restrict__ o_sas,
    float* __restrict__ state)
{
    const int b = blockIdx.x, tid = threadIdx.x;
    __shared__ float v_[128], mn[64], sd[64], zz[2][64], hh1[200], hh2[100];
    if (tid < 128) v_[tid] = vf[b * 128 + tid];
    __syncthreads();
    if (tid < 128) {
        int j = tid & 63;
        bool isv = tid >= 64;
        const float* W = (isv ? Wv : Wm) + j * 128;
        float a = isv ? bv[j] : bm[j];
#pragma unroll 4
        for (int k = 0; k < 128; ++k) a = fmaf(v_[k], W[k], a);
        if (!isv) { mn[j] = a; o_mean[b * 64 + j] = a; }
        else      { float s = __expf(0.5f * a); sd[j] = s; o_std[b * 64 + j] = s; }
    }
    __syncthreads();
    if (tid < 128) {
        int l = tid >> 6, j = tid & 63;
        float zv = fmaf(noise[(l * 32 + b) * 64 + j], sd[j], mn[j]);
        zz[l][j] = zv;
        o_z[(l * 32 + b) * 64 + j] = zv;
    }
    __syncthreads();
#pragma unroll
    for (int p = 0; p < 4; ++p) {
        int tt = p * 256 + tid;
        int l = tt >> 9, hd = tt & 511;
        const float* W = Wl2r + hd * 64;
        float a = bl2r[hd];
#pragma unroll 4
        for (int k = 0; k < 64; ++k) a = fmaf(zz[l][k], W[k], a);
        state[(size_t)(l * 32 + b) * 512 + hd] = a;
    }
    if (tid < 200) {
        const float* W = lW1 + tid * 64;
        float a = lb1[tid];
        for (int k = 0; k < 64; ++k) a = fmaf(mn[k], W[k], a);
        hh1[tid] = fmaxf(a, 0.f);
    }
    __syncthreads();
    if (tid < 100) {
        const float* W = lW2 + tid * 200;
        float a = lb2[tid];
        for (int k = 0; k < 200; ++k) a = fmaf(hh1[k], W[k], a);
        hh2[tid] = fmaxf(a, 0.f);
    }
    __syncthreads();
    if (tid == 0) {
        float a = lb3[0];
        for (int k = 0; k < 100; ++k) a = fmaf(hh2[k], lW3[k], a);
        o_logp[b] = a;
    }
    __syncthreads();
    if (tid < 200) {
        const float* W = sW1 + tid * 64;
        float a = sb1[tid];
        for (int k = 0; k < 64; ++k) a = fmaf(mn[k], W[k], a);
        hh1[tid] = fmaxf(a, 0.f);
    }
    __syncthreads();
    if (tid < 100) {
        const float* W = sW2 + tid * 200;
        float a = sb2[tid];
        for (int k = 0; k < 200; ++k) a = fmaf(hh1[k], W[k], a);
        hh2[tid] = fmaxf(a, 0.f);
    }
    __syncthreads();
    if (tid == 0) {
        float a = sb3[0];
        for (int k = 0; k < 100; ++k) a = fmaf(hh2[k], sW3[k], a);
        o_sas[b] = a;
    }
}

// ---------------- bf16 MFMA GEMM: C(MxN,f32) = A(MxK) * B(NxK)^T + bias ----------------
__global__ __launch_bounds__(256) void gemm_bt_kernel(
    const unsigned short* __restrict__ A,
    const unsigned short* __restrict__ B,
    const float* __restrict__ bias,
    float* __restrict__ C,
    int M, int N, int K)
{
    __shared__ unsigned short lA[128 * 64];
    __shared__ unsigned short lB[128 * 64];
    const int tid = threadIdx.x;
    const int lane = tid & 63;
    const int wave = tid >> 6;
    const int wm = wave >> 1, wn = wave & 1;
    const int m0 = blockIdx.y * 128, n0 = blockIdx.x * 128;

    f32x4_t acc[4][4];
#pragma unroll
    for (int i = 0; i < 4; ++i)
#pragma unroll
        for (int j = 0; j < 4; ++j) acc[i][j] = (f32x4_t){0.f, 0.f, 0.f, 0.f};

    for (int kt = 0; kt < K; kt += 64) {
#pragma unroll
        for (int p = 0; p < 4; ++p) {
            int g = p * 256 + tid;
            int row = g >> 3, c8 = g & 7;
            int dst = row * 64 + ((c8 ^ (row & 7)) << 3);
            *(u16x8_t*)&lA[dst] = *(const u16x8_t*)(A + (size_t)(m0 + row) * K + kt + (c8 << 3));
            *(u16x8_t*)&lB[dst] = *(const u16x8_t*)(B + (size_t)(n0 + row) * K + kt + (c8 << 3));
        }
        __syncthreads();
#pragma unroll
        for (int kc = 0; kc < 2; ++kc) {
            bf16x8_t af[4], bfr[4];
            int c8 = kc * 4 + (lane >> 4);
#pragma unroll
            for (int i = 0; i < 4; ++i) {
                int ra = wm * 64 + i * 16 + (lane & 15);
                af[i] = *(const bf16x8_t*)&lA[ra * 64 + ((c8 ^ (ra & 7)) << 3)];
                int rb = wn * 64 + i * 16 + (lane & 15);
                bfr[i] = *(const bf16x8_t*)&lB[rb * 64 + ((c8 ^ (rb & 7)) << 3)];
            }
#pragma unroll
            for (int i = 0; i < 4; ++i)
#pragma unroll
                for (int j = 0; j < 4; ++j)
                    acc[i][j] = __builtin_amdgcn_mfma_f32_16x16x32_bf16(af[i], bfr[j], acc[i][j], 0, 0, 0);
        }
        __syncthreads();
    }
    const int lm = (lane >> 4) * 4, ln = lane & 15;
#pragma unroll
    for (int i = 0; i < 4; ++i) {
        int gm = m0 + wm * 64 + i * 16 + lm;
#pragma unroll
        for (int j = 0; j < 4; ++j) {
            int gn = n0 + wn * 64 + j * 16 + ln;
            float bb = bias ? bias[gn] : 0.f;
#pragma unroll
            for (int r = 0; r < 4; ++r)
                C[(size_t)(gm + r) * N + gn] = acc[i][j][r] + bb;
        }
    }
}

// ---------------- GRU scan, MFMA + grid barrier ----------------
// 64 WGs = (2 batch-halves of 16) x (32 d-slices of 16). 192 threads (3 waves,
// one per gate). Whh slice (48 rows x 512) lives in LDS as f16 B-fragments,
// loaded once. h kept in f32 registers (one (b,d) per thread), republished as
// f16 to a double-buffered global array each step. One device barrier / step.
#define NWG_SCAN 64

__global__ __launch_bounds__(192) void gru_scan_mfma_kernel(
    const float* __restrict__ xW,      // 2048 x 1536 (x@Wih^T + bih)
    const float* __restrict__ Whh,     // 1536 x 512 f32
    const float* __restrict__ bhh,     // 1536
    const float* __restrict__ h0,      // 32 x 512 f32
    const int* __restrict__ lengths,   // 32 (sorted descending)
    unsigned short* __restrict__ hbuf, // 2 x 32 x 512 f16 bits (double buffer)
    unsigned short* __restrict__ outb, // 2048 x 512 bf16 (masked rows = 0)
    int* __restrict__ cnt)             // barrier counter (zeroed before launch)
{
    __shared__ unsigned short Wl[3 * 16 * 64 * 8];  // 48 KB: [gate][kk][lane][8] f16
    __shared__ float Csm[3][16][17];                // hW tiles, padded
    const int tid = threadIdx.x;
    const int w = blockIdx.x;
    const int b0 = (w >> 5) * 16;   // batch-half base
    const int d0 = (w & 31) * 16;   // d-slice base
    const int lane = tid & 63;
    const int gi = tid >> 6;        // wave index = gate (0=r,1=z,2=n)

    // ---- preload Whh slice into LDS as f16 fragments (once) ----
    for (int idx = tid; idx < 3 * 16 * 64; idx += 192) {
        int g_ = idx >> 10;
        int rem = idx & 1023;
        int kk = rem >> 6, ln = rem & 63;
        int grow = g_ * 512 + d0 + (ln & 15);
        int k = kk * 32 + ((ln >> 4) << 3);
        const float* src = Whh + (size_t)grow * 512 + k;
        f16x8_t v;
#pragma unroll
        for (int j = 0; j < 8; ++j) v[j] = (_Float16)src[j];
        *(f16x8_t*)&Wl[idx << 3] = v;
    }

    // ---- per-thread items: i0 = tid (0..191), i1 = 192+tid (tid<64) ----
    const bool has1 = (tid < 64);
    const int b_0 = tid >> 4, dd0 = tid & 15;
    const int i1 = 192 + tid;
    const int b_1 = i1 >> 4, dd1 = i1 & 15;
    const int gb0 = b0 + b_0, gb1 = b0 + b_1;
    const float bhr0 = bhh[d0 + dd0], bhz0 = bhh[512 + d0 + dd0], bhn0 = bhh[1024 + d0 + dd0];
    float bhr1 = 0.f, bhz1 = 0.f, bhn1 = 0.f;
    const int len0i = lengths[gb0];
    int len1i = 0;
    float hr0 = h0[(size_t)gb0 * 512 + d0 + dd0];
    float hr1 = 0.f;
    hbuf[gb0 * 512 + d0 + dd0] = f2h(hr0);
    if (has1) {
        bhr1 = bhh[d0 + dd1]; bhz1 = bhh[512 + d0 + dd1]; bhn1 = bhh[1024 + d0 + dd1];
        len1i = lengths[gb1];
        hr1 = h0[(size_t)gb1 * 512 + d0 + dd1];
        hbuf[gb1 * 512 + d0 + dd1] = f2h(hr1);
    }
    const int lenb0 = lengths[b0];  // WG-uniform activity bound (sorted desc)

    for (int t = 0; t < 64; ++t) {
        // ---- device barrier (release h writes of step t-1 / init) ----
        __syncthreads();
        if (tid == 0) {
            __threadfence();
            atomicAdd(cnt, 1);
            const int tgt = NWG_SCAN * (t + 1);
            while (__hip_atomic_load(cnt, __ATOMIC_RELAXED, __HIP_MEMORY_SCOPE_AGENT) < tgt)
                __builtin_amdgcn_s_sleep(2);
        }
        __syncthreads();
        __threadfence();  // acquire: invalidate caches before reading peers' h

        if (t < lenb0) {
            // ---- hW = h @ Whh^T for (16 b x 16 d) of this gate ----
            const unsigned short* hc = hbuf + ((t & 1) << 14);
            f32x4_t acc = (f32x4_t){0.f, 0.f, 0.f, 0.f};
            const int lb = b0 + (lane & 15);
            const int lk = (lane >> 4) << 3;
#pragma unroll
            for (int kk = 0; kk < 16; ++kk) {
                f16x8_t af = *(const f16x8_t*)(hc + lb * 512 + kk * 32 + lk);
                f16x8_t bf = *(const f16x8_t*)&Wl[((gi * 16 + kk) * 64 + lane) << 3];
                acc = __builtin_amdgcn_mfma_f32_16x16x32_f16(af, bf, acc, 0, 0, 0);
            }
            const int rr = (lane >> 4) << 2, cc = lane & 15;
#pragma unroll
            for (int r = 0; r < 4; ++r) Csm[gi][rr + r][cc] = acc[r];
        }
        __syncthreads();

        // ---- gate update (each thread owns 1-2 (b,d) items) ----
        {
            size_t orow = (size_t)(gb0 * 64 + t) * 512 + d0 + dd0;
            if (t < len0i) {
                float hr = Csm[0][b_0][dd0], hz = Csm[1][b_0][dd0], hn = Csm[2][b_0][dd0];
                const float* xp = xW + (size_t)(gb0 * 64 + t) * 1536 + d0 + dd0;
                float r = sigmoidf_(xp[0] + hr + bhr0);
                float u = sigmoidf_(xp[512] + hz + bhz0);
                float n = tanhf(xp[1024] + r * (hn + bhn0));
                hr0 = (1.f - u) * n + u * hr0;
                hbuf[(((t + 1) & 1) << 14) + gb0 * 512 + d0 + dd0] = f2h(hr0);
                outb[orow] = f2bf(hr0);
            } else {
                outb[orow] = 0;
            }
        }
        if (has1) {
            size_t orow = (size_t)(gb1 * 64 + t) * 512 + d0 + dd1;
            if (t < len1i) {
                float hr = Csm[0][b_1][dd1], hz = Csm[1][b_1][dd1], hn = Csm[2][b_1][dd1];
                const float* xp = xW + (size_t)(gb1 * 64 + t) * 1536 + d0 + dd1;
                float r = sigmoidf_(xp[0] + hr + bhr1);
                float u = sigmoidf_(xp[512] + hz + bhz1);
                float n = tanhf(xp[1024] + r * (hn + bhn1));
                hr1 = (1.f - u) * n + u * hr1;
                hbuf[(((t + 1) & 1) << 14) + gb1 * 512 + d0 + dd1] = f2h(hr1);
                outb[orow] = f2bf(hr1);
            } else {
                outb[orow] = 0;
            }
        }
    }
}

extern "C" void kernel_launch(void* const* d_in, const int* in_sizes, int n_in,
                              void* d_out, int out_size, void* d_ws, size_t ws_size,
                              hipStream_t stream) {
    const int*   tok    = (const int*)d_in[0];
    const int*   lens   = (const int*)d_in[1];
    const float* noise  = (const float*)d_in[2];
    const float* table  = (const float*)d_in[3];
    const float* Wm     = (const float*)d_in[4];
    const float* bm_    = (const float*)d_in[5];
    const float* Wv     = (const float*)d_in[6];
    const float* bv_    = (const float*)d_in[7];
    const float* Wl2r   = (const float*)d_in[8];
    const float* bl2r   = (const float*)d_in[9];
    const float* Wih0   = (const float*)d_in[10];
    const float* Whh0   = (const float*)d_in[11];
    const float* bih0   = (const float*)d_in[12];
    const float* bhh0   = (const float*)d_in[13];
    const float* Wih1   = (const float*)d_in[14];
    const float* Whh1   = (const float*)d_in[15];
    const float* bih1   = (const float*)d_in[16];
    const float* bhh1   = (const float*)d_in[17];
    const float* Wout   = (const float*)d_in[18];
    const float* bout   = (const float*)d_in[19];
    const float* lW1 = (const float*)d_in[20]; const float* lb1 = (const float*)d_in[21];
    const float* lW2 = (const float*)d_in[22]; const float* lb2 = (const float*)d_in[23];
    const float* lW3 = (const float*)d_in[24]; const float* lb3 = (const float*)d_in[25];
    const float* sW1 = (const float*)d_in[26]; const float* sb1 = (const float*)d_in[27];
    const float* sW2 = (const float*)d_in[28]; const float* sb2 = (const float*)d_in[29];
    const float* sW3 = (const float*)d_in[30]; const float* sb3 = (const float*)d_in[31];

    float* out    = (float*)d_out;           // (B,S,V) = 2048 x 32000
    float* o_mean = out + 65536000;
    float* o_std  = o_mean + 2048;
    float* o_z    = o_std + 2048;
    float* o_logp = o_z + 4096;
    float* o_sas  = o_logp + 32;

    char* ws = (char*)d_ws;
    unsigned short* Woutb = (unsigned short*)ws;  ws += 32768000;  // 32000x512 bf16
    unsigned short* Wih0b = (unsigned short*)ws;  ws += 393216;    // 1536x128 bf16
    unsigned short* Wih1b = (unsigned short*)ws;  ws += 1572864;   // 1536x512 bf16
    unsigned short* embb  = (unsigned short*)ws;  ws += 524288;    // 2048x128 bf16
    float*          vf    = (float*)ws;           ws += 16384;     // 32x128
    float*          state = (float*)ws;           ws += 131072;    // 2x32x512
    float*          xW    = (float*)ws;           ws += 12582912;  // 2048x1536 f32 (reused)
    unsigned short* out0b = (unsigned short*)ws;  ws += 2097152;   // 2048x512 bf16
    unsigned short* out1b = (unsigned short*)ws;  ws += 2097152;
    unsigned short* hbuf  = (unsigned short*)ws;  ws += 65536;     // 2x32x512 f16
    int*            cntp  = (int*)ws;             ws += 256;       // 2 barrier counters

    // weight preprocessing (input-independent)
    cvt_bf16_kernel<<<dim3(4096), dim3(256), 0, stream>>>(Wout, Woutb, 16384000 / 4);
    cvt_bf16_kernel<<<dim3(192),  dim3(256), 0, stream>>>(Wih0, Wih0b, 196608 / 4);
    cvt_bf16_kernel<<<dim3(768),  dim3(256), 0, stream>>>(Wih1, Wih1b, 786432 / 4);
    hipMemsetAsync(cntp, 0, 8, stream);  // zero both barrier counters

    // encoder path
    embed_kernel<<<dim3(32), dim3(128), 0, stream>>>(tok, table, embb, vf);
    encoder_kernel<<<dim3(32), dim3(256), 0, stream>>>(vf, Wm, bm_, Wv, bv_, noise, Wl2r, bl2r,
                                                       lW1, lb1, lW2, lb2, lW3, lb3,
                                                       sW1, sb1, sW2, sb2, sW3, sb3,
                                                       o_mean, o_std, o_z, o_logp, o_sas, state);

    // GRU layer 0
    gemm_bt_kernel<<<dim3(12, 16), dim3(256), 0, stream>>>(embb, Wih0b, bih0, xW, 2048, 1536, 128);
    gru_scan_mfma_kernel<<<dim3(NWG_SCAN), dim3(192), 0, stream>>>(
        xW, Whh0, bhh0, state, lens, hbuf, out0b, cntp);
    // GRU layer 1
    gemm_bt_kernel<<<dim3(12, 16), dim3(256), 0, stream>>>(out0b, Wih1b, bih1, xW, 2048, 1536, 512);
    gru_scan_mfma_kernel<<<dim3(NWG_SCAN), dim3(192), 0, stream>>>(
        xW, Whh1, bhh1, state + 16384, lens, hbuf, out1b, cntp + 1);

    // output projection (B,S,V)
    gemm_bt_kernel<<<dim3(250, 16), dim3(256), 0, stream>>>(out1b, Woutb, bout, out, 2048, 32000, 512);
}

// Round 4
// 1286.247 us; speedup vs baseline: 2.6620x; 1.0532x over previous
//
#include <hip/hip_runtime.h>

// Frag2Mol: embed -> encoder(VAE) -> 2x GRU(scan over T=64) -> vocab GEMM.
// Sizes: B=32 S=64 V=32000 E=128 H=512 L=2 LAT=64.
// r4: fix r3 h-read row stride (hbuf row = 512 f16 = 128 ull words; r3 used
//     64 -> wrong batches' h in A-fragments, absmax 1.4). Everything else
//     identical to r3 (agent-scope atomic exchange, 32 WGs x 384 thr).

typedef __attribute__((ext_vector_type(8))) short bf16x8_t;
typedef __attribute__((ext_vector_type(8))) unsigned short u16x8_t;
typedef __attribute__((ext_vector_type(4))) float f32x4_t;
typedef __attribute__((ext_vector_type(8))) _Float16 f16x8_t;
typedef __attribute__((ext_vector_type(2))) unsigned long long ullx2_t;

#define AS_AGENT __HIP_MEMORY_SCOPE_AGENT

static __device__ __forceinline__ unsigned short f2bf(float f) {
    unsigned int u = __float_as_uint(f);
    u += 0x7fffu + ((u >> 16) & 1u);
    return (unsigned short)(u >> 16);
}
static __device__ __forceinline__ unsigned short f2h(float f) {
    _Float16 h = (_Float16)f;
    return __builtin_bit_cast(unsigned short, h);
}
static __device__ __forceinline__ float sigmoidf_(float x) {
    return 1.f / (1.f + __expf(-x));
}

// ---------------- f32 -> bf16 convert (n multiple of 4) ----------------
__global__ __launch_bounds__(256) void cvt_bf16_kernel(const float* __restrict__ in,
                                                       unsigned short* __restrict__ out, int n4) {
    int stride = gridDim.x * 256;
    for (int i = blockIdx.x * 256 + threadIdx.x; i < n4; i += stride) {
        float4 v = reinterpret_cast<const float4*>(in)[i];
        ushort4 o;
        o.x = f2bf(v.x); o.y = f2bf(v.y); o.z = f2bf(v.z); o.w = f2bf(v.w);
        reinterpret_cast<ushort4*>(out)[i] = o;
    }
}

// ---------------- embedding + masked sum ----------------
__global__ __launch_bounds__(128) void embed_kernel(const int* __restrict__ tok,
                                                    const float* __restrict__ table,
                                                    unsigned short* __restrict__ embb,
                                                    float* __restrict__ vf) {
    const int b = blockIdx.x, e = threadIdx.x;
    float acc = 0.f;
    for (int s = 0; s < 64; ++s) {
        int id = tok[b * 64 + s];
        float v = table[(size_t)id * 128 + e];
        embb[(size_t)(b * 64 + s) * 128 + e] = f2bf(v);
        if (id > 2) acc += v;
    }
    vf[b * 128 + e] = acc;
}

// ---------------- encoder: mean/std/z, state = z@Wl2r^T, 2 MLPs ----------------
__global__ __launch_bounds__(256) void encoder_kernel(
    const float* __restrict__ vf,
    const float* __restrict__ Wm, const float* __restrict__ bm,
    const float* __restrict__ Wv, const float* __restrict__ bv,
    const float* __restrict__ noise,
    const float* __restrict__ Wl2r, const float* __restrict__ bl2r,
    const float* __restrict__ lW1, const float* __restrict__ lb1,
    const float* __restrict__ lW2, const float* __restrict__ lb2,
    const float* __restrict__ lW3, const float* __restrict__ lb3,
    const float* __restrict__ sW1, const float* __restrict__ sb1,
    const float* __restrict__ sW2, const float* __restrict__ sb2,
    const float* __restrict__ sW3, const float* __restrict__ sb3,
    float* __restrict__ o_mean, float* __restrict__ o_std, float* __restrict__ o_z,
    float* __restrict__ o_logp, float* __restrict__ o_sas,
    float* __restrict__ state)
{
    const int b = blockIdx.x, tid = threadIdx.x;
    __shared__ float v_[128], mn[64], sd[64], zz[2][64], hh1[200], hh2[100];
    if (tid < 128) v_[tid] = vf[b * 128 + tid];
    __syncthreads();
    if (tid < 128) {
        int j = tid & 63;
        bool isv = tid >= 64;
        const float* W = (isv ? Wv : Wm) + j * 128;
        float a = isv ? bv[j] : bm[j];
#pragma unroll 4
        for (int k = 0; k < 128; ++k) a = fmaf(v_[k], W[k], a);
        if (!isv) { mn[j] = a; o_mean[b * 64 + j] = a; }
        else      { float s = __expf(0.5f * a); sd[j] = s; o_std[b * 64 + j] = s; }
    }
    __syncthreads();
    if (tid < 128) {
        int l = tid >> 6, j = tid & 63;
        float zv = fmaf(noise[(l * 32 + b) * 64 + j], sd[j], mn[j]);
        zz[l][j] = zv;
        o_z[(l * 32 + b) * 64 + j] = zv;
    }
    __syncthreads();
#pragma unroll
    for (int p = 0; p < 4; ++p) {
        int tt = p * 256 + tid;
        int l = tt >> 9, hd = tt & 511;
        const float* W = Wl2r + hd * 64;
        float a = bl2r[hd];
#pragma unroll 4
        for (int k = 0; k < 64; ++k) a = fmaf(zz[l][k], W[k], a);
        state[(size_t)(l * 32 + b) * 512 + hd] = a;
    }
    if (tid < 200) {
        const float* W = lW1 + tid * 64;
        float a = lb1[tid];
        for (int k = 0; k < 64; ++k) a = fmaf(mn[k], W[k], a);
        hh1[tid] = fmaxf(a, 0.f);
    }
    __syncthreads();
    if (tid < 100) {
        const float* W = lW2 + tid * 200;
        float a = lb2[tid];
        for (int k = 0; k < 200; ++k) a = fmaf(hh1[k], W[k], a);
        hh2[tid] = fmaxf(a, 0.f);
    }
    __syncthreads();
    if (tid == 0) {
        float a = lb3[0];
        for (int k = 0; k < 100; ++k) a = fmaf(hh2[k], lW3[k], a);
        o_logp[b] = a;
    }
    __syncthreads();
    if (tid < 200) {
        const float* W = sW1 + tid * 64;
        float a = sb1[tid];
        for (int k = 0; k < 64; ++k) a = fmaf(mn[k], W[k], a);
        hh1[tid] = fmaxf(a, 0.f);
    }
    __syncthreads();
    if (tid < 100) {
        const float* W = sW2 + tid * 200;
        float a = sb2[tid];
        for (int k = 0; k < 200; ++k) a = fmaf(hh1[k], W[k], a);
        hh2[tid] = fmaxf(a, 0.f);
    }
    __syncthreads();
    if (tid == 0) {
        float a = sb3[0];
        for (int k = 0; k < 100; ++k) a = fmaf(hh2[k], sW3[k], a);
        o_sas[b] = a;
    }
}

// ---------------- bf16 MFMA GEMM: C(MxN,f32) = A(MxK) * B(NxK)^T + bias ----------------
__global__ __launch_bounds__(256) void gemm_bt_kernel(
    const unsigned short* __restrict__ A,
    const unsigned short* __restrict__ B,
    const float* __restrict__ bias,
    float* __restrict__ C,
    int M, int N, int K)
{
    __shared__ unsigned short lA[128 * 64];
    __shared__ unsigned short lB[128 * 64];
    const int tid = threadIdx.x;
    const int lane = tid & 63;
    const int wave = tid >> 6;
    const int wm = wave >> 1, wn = wave & 1;
    const int m0 = blockIdx.y * 128, n0 = blockIdx.x * 128;

    f32x4_t acc[4][4];
#pragma unroll
    for (int i = 0; i < 4; ++i)
#pragma unroll
        for (int j = 0; j < 4; ++j) acc[i][j] = (f32x4_t){0.f, 0.f, 0.f, 0.f};

    for (int kt = 0; kt < K; kt += 64) {
#pragma unroll
        for (int p = 0; p < 4; ++p) {
            int g = p * 256 + tid;
            int row = g >> 3, c8 = g & 7;
            int dst = row * 64 + ((c8 ^ (row & 7)) << 3);
            *(u16x8_t*)&lA[dst] = *(const u16x8_t*)(A + (size_t)(m0 + row) * K + kt + (c8 << 3));
            *(u16x8_t*)&lB[dst] = *(const u16x8_t*)(B + (size_t)(n0 + row) * K + kt + (c8 << 3));
        }
        __syncthreads();
#pragma unroll
        for (int kc = 0; kc < 2; ++kc) {
            bf16x8_t af[4], bfr[4];
            int c8 = kc * 4 + (lane >> 4);
#pragma unroll
            for (int i = 0; i < 4; ++i) {
                int ra = wm * 64 + i * 16 + (lane & 15);
                af[i] = *(const bf16x8_t*)&lA[ra * 64 + ((c8 ^ (ra & 7)) << 3)];
                int rb = wn * 64 + i * 16 + (lane & 15);
                bfr[i] = *(const bf16x8_t*)&lB[rb * 64 + ((c8 ^ (rb & 7)) << 3)];
            }
#pragma unroll
            for (int i = 0; i < 4; ++i)
#pragma unroll
                for (int j = 0; j < 4; ++j)
                    acc[i][j] = __builtin_amdgcn_mfma_f32_16x16x32_bf16(af[i], bfr[j], acc[i][j], 0, 0, 0);
        }
        __syncthreads();
    }
    const int lm = (lane >> 4) * 4, ln = lane & 15;
#pragma unroll
    for (int i = 0; i < 4; ++i) {
        int gm = m0 + wm * 64 + i * 16 + lm;
#pragma unroll
        for (int j = 0; j < 4; ++j) {
            int gn = n0 + wn * 64 + j * 16 + ln;
            float bb = bias ? bias[gn] : 0.f;
#pragma unroll
            for (int r = 0; r < 4; ++r)
                C[(size_t)(gm + r) * N + gn] = acc[i][j][r] + bb;
        }
    }
}

// ---------------- GRU scan, MFMA + fine-grained atomic barrier ----------------
// 32 WGs (one per 16-d slice), 384 threads = 6 waves = (3 gates) x (2 M-tiles).
// Whh slice (48 rows x 512 f16 = 48 KB) in LDS, loaded once. h exchanged via
// agent-scope relaxed atomics (bypass non-coherent L2) double-buffered in hbuf.
// Barrier: per-WG arrive (atomicAdd) after explicit vmcnt(0); per-wave poll.
#define NWG_SCAN 32

__global__ __launch_bounds__(384) void gru_scan_mfma_kernel(
    const float* __restrict__ xW,      // 2048 x 1536 (x@Wih^T + bih)
    const float* __restrict__ Whh,     // 1536 x 512 f32
    const float* __restrict__ bhh,     // 1536
    const float* __restrict__ h0,      // 32 x 512 f32
    const int* __restrict__ lengths,   // 32
    unsigned short* __restrict__ hbuf, // 2 x 32 x 512 f16 (double buffer)
    unsigned short* __restrict__ outb, // 2048 x 512 bf16 (masked rows = 0)
    int* __restrict__ cnt)             // barrier counter (zeroed before launch)
{
    __shared__ unsigned short Wl[3 * 16 * 64 * 8];  // 48 KB f16 fragments
    __shared__ float Csm[3][32][17];                // [gate][batch][d] padded
    const int tid = threadIdx.x;
    const int d0 = blockIdx.x * 16;
    const int lane = tid & 63;
    const int wave = tid >> 6;          // 0..5
    const int gate = wave >> 1;         // 0=r 1=z 2=n
    const int mt = wave & 1;            // M-tile (batches 0-15 / 16-31)

    // ---- preload Whh slice into LDS as f16 fragments (once) ----
    for (int idx = tid; idx < 3 * 16 * 64; idx += 384) {
        int g_ = idx >> 10;
        int rem = idx & 1023;
        int kk = rem >> 6, ln = rem & 63;
        int grow = g_ * 512 + d0 + (ln & 15);
        int k = kk * 32 + ((ln >> 4) << 3);
        const float* src = Whh + (size_t)grow * 512 + k;
        f16x8_t v;
#pragma unroll
        for (int j = 0; j < 8; ++j) v[j] = (_Float16)src[j];
        *(f16x8_t*)&Wl[idx << 3] = v;
    }

    // ---- update-phase ownership: thread i<256 owns (b = i>>3, d-pair dp = 2*(i&7)) ----
    const bool upd = (tid < 256);
    const int ub = tid >> 3;
    const int udp = (tid & 7) * 2;
    unsigned int* __restrict__ hb32 = (unsigned int*)hbuf;
    unsigned int* __restrict__ ob32 = (unsigned int*)outb;
    float h_lo = 0.f, h_hi = 0.f;
    float br_lo = 0.f, br_hi = 0.f, bz_lo = 0.f, bz_hi = 0.f, bn_lo = 0.f, bn_hi = 0.f;
    int lenb = 0;
    if (upd) {
        h_lo = h0[(size_t)ub * 512 + d0 + udp];
        h_hi = h0[(size_t)ub * 512 + d0 + udp + 1];
        br_lo = bhh[d0 + udp];        br_hi = bhh[d0 + udp + 1];
        bz_lo = bhh[512 + d0 + udp];  bz_hi = bhh[512 + d0 + udp + 1];
        bn_lo = bhh[1024 + d0 + udp]; bn_hi = bhh[1024 + d0 + udp + 1];
        lenb = lengths[ub];
        unsigned int hw = (unsigned int)f2h(h_lo) | ((unsigned int)f2h(h_hi) << 16);
        __hip_atomic_store(&hb32[ub * 256 + ((d0 + udp) >> 1)], hw, __ATOMIC_RELAXED, AS_AGENT);
    }
    asm volatile("s_waitcnt vmcnt(0)" ::: "memory");
    __syncthreads();
    if (tid == 0) __hip_atomic_fetch_add(cnt, 1, __ATOMIC_RELAXED, AS_AGENT);

    // ---- MFMA-phase constants ----
    const unsigned long long* __restrict__ hb64 = (const unsigned long long*)hbuf;
    const int brow = mt * 16 + (lane & 15);   // A-row (batch)
    const int ko = lane >> 4;                 // k-subchunk 0..3

    for (int t = 0; t < 64; ++t) {
        // ---- poll: all step-(t-1) publishes visible ----
        {
            const int tgt = NWG_SCAN * (t + 1);
            int v;
            for (;;) {
                v = 0;
                if (lane == 0) v = __hip_atomic_load(cnt, __ATOMIC_RELAXED, AS_AGENT);
                v = __builtin_amdgcn_readfirstlane(v);
                if (v >= tgt) break;
                __builtin_amdgcn_s_sleep(1);
            }
        }
        // ---- hW = h @ Whh^T : one 16x16 tile per wave ----
        {
            // row stride: 512 f16 = 128 ull words  (r3 bug: used 64)
            const unsigned long long* hb = hb64 + (size_t)(t & 1) * 4096 + (size_t)brow * 128;
            f32x4_t acc = (f32x4_t){0.f, 0.f, 0.f, 0.f};
#pragma unroll
            for (int kk = 0; kk < 16; ++kk) {
                int j0 = kk * 8 + ko * 2;
                unsigned long long lo = __hip_atomic_load(&hb[j0], __ATOMIC_RELAXED, AS_AGENT);
                unsigned long long hi = __hip_atomic_load(&hb[j0 + 1], __ATOMIC_RELAXED, AS_AGENT);
                ullx2_t u; u[0] = lo; u[1] = hi;
                f16x8_t af = __builtin_bit_cast(f16x8_t, u);
                f16x8_t bf = *(const f16x8_t*)&Wl[((gate * 16 + kk) * 64 + lane) << 3];
                acc = __builtin_amdgcn_mfma_f32_16x16x32_f16(af, bf, acc, 0, 0, 0);
            }
            const int crow = mt * 16 + ((lane >> 4) << 2), ccol = lane & 15;
#pragma unroll
            for (int r = 0; r < 4; ++r) Csm[gate][crow + r][ccol] = acc[r];
        }
        __syncthreads();

        // ---- gate update: thread owns (ub, d0+udp, d0+udp+1) ----
        if (upd) {
            size_t orow = (size_t)(ub * 64 + t) * 256 + ((d0 + udp) >> 1);
            if (t < lenb) {
                const float* xp = xW + (size_t)(ub * 64 + t) * 1536 + d0 + udp;
                float2 x_r = *(const float2*)xp;
                float2 x_z = *(const float2*)(xp + 512);
                float2 x_n = *(const float2*)(xp + 1024);
                float hr_lo = Csm[0][ub][udp], hr_hi = Csm[0][ub][udp + 1];
                float hz_lo = Csm[1][ub][udp], hz_hi = Csm[1][ub][udp + 1];
                float hn_lo = Csm[2][ub][udp], hn_hi = Csm[2][ub][udp + 1];
                float r0 = sigmoidf_(x_r.x + hr_lo + br_lo);
                float r1 = sigmoidf_(x_r.y + hr_hi + br_hi);
                float u0 = sigmoidf_(x_z.x + hz_lo + bz_lo);
                float u1 = sigmoidf_(x_z.y + hz_hi + bz_hi);
                float n0 = tanhf(x_n.x + r0 * (hn_lo + bn_lo));
                float n1 = tanhf(x_n.y + r1 * (hn_hi + bn_hi));
                h_lo = (1.f - u0) * n0 + u0 * h_lo;
                h_hi = (1.f - u1) * n1 + u1 * h_hi;
                ob32[orow] = (unsigned int)f2bf(h_lo) | ((unsigned int)f2bf(h_hi) << 16);
            } else {
                ob32[orow] = 0u;
            }
            unsigned int hw = (unsigned int)f2h(h_lo) | ((unsigned int)f2h(h_hi) << 16);
            __hip_atomic_store(&hb32[((t + 1) & 1) * 8192 + ub * 256 + ((d0 + udp) >> 1)],
                               hw, __ATOMIC_RELAXED, AS_AGENT);
        }
        asm volatile("s_waitcnt vmcnt(0)" ::: "memory");
        __syncthreads();
        if (tid == 0) __hip_atomic_fetch_add(cnt, 1, __ATOMIC_RELAXED, AS_AGENT);
    }
}

extern "C" void kernel_launch(void* const* d_in, const int* in_sizes, int n_in,
                              void* d_out, int out_size, void* d_ws, size_t ws_size,
                              hipStream_t stream) {
    const int*   tok    = (const int*)d_in[0];
    const int*   lens   = (const int*)d_in[1];
    const float* noise  = (const float*)d_in[2];
    const float* table  = (const float*)d_in[3];
    const float* Wm     = (const float*)d_in[4];
    const float* bm_    = (const float*)d_in[5];
    const float* Wv     = (const float*)d_in[6];
    const float* bv_    = (const float*)d_in[7];
    const float* Wl2r   = (const float*)d_in[8];
    const float* bl2r   = (const float*)d_in[9];
    const float* Wih0   = (const float*)d_in[10];
    const float* Whh0   = (const float*)d_in[11];
    const float* bih0   = (const float*)d_in[12];
    const float* bhh0   = (const float*)d_in[13];
    const float* Wih1   = (const float*)d_in[14];
    const float* Whh1   = (const float*)d_in[15];
    const float* bih1   = (const float*)d_in[16];
    const float* bhh1   = (const float*)d_in[17];
    const float* Wout   = (const float*)d_in[18];
    const float* bout   = (const float*)d_in[19];
    const float* lW1 = (const float*)d_in[20]; const float* lb1 = (const float*)d_in[21];
    const float* lW2 = (const float*)d_in[22]; const float* lb2 = (const float*)d_in[23];
    const float* lW3 = (const float*)d_in[24]; const float* lb3 = (const float*)d_in[25];
    const float* sW1 = (const float*)d_in[26]; const float* sb1 = (const float*)d_in[27];
    const float* sW2 = (const float*)d_in[28]; const float* sb2 = (const float*)d_in[29];
    const float* sW3 = (const float*)d_in[30]; const float* sb3 = (const float*)d_in[31];

    float* out    = (float*)d_out;           // (B,S,V) = 2048 x 32000
    float* o_mean = out + 65536000;
    float* o_std  = o_mean + 2048;
    float* o_z    = o_std + 2048;
    float* o_logp = o_z + 4096;
    float* o_sas  = o_logp + 32;

    char* ws = (char*)d_ws;
    unsigned short* Woutb = (unsigned short*)ws;  ws += 32768000;  // 32000x512 bf16
    unsigned short* Wih0b = (unsigned short*)ws;  ws += 393216;    // 1536x128 bf16
    unsigned short* Wih1b = (unsigned short*)ws;  ws += 1572864;   // 1536x512 bf16
    unsigned short* embb  = (unsigned short*)ws;  ws += 524288;    // 2048x128 bf16
    float*          vf    = (float*)ws;           ws += 16384;     // 32x128
    float*          state = (float*)ws;           ws += 131072;    // 2x32x512
    float*          xW    = (float*)ws;           ws += 12582912;  // 2048x1536 f32 (reused)
    unsigned short* out0b = (unsigned short*)ws;  ws += 2097152;   // 2048x512 bf16
    unsigned short* out1b = (unsigned short*)ws;  ws += 2097152;
    unsigned short* hbuf  = (unsigned short*)ws;  ws += 65536;     // 2x32x512 f16
    int*            cntp  = (int*)ws;             ws += 256;       // 2 barrier counters

    // weight preprocessing (input-independent)
    cvt_bf16_kernel<<<dim3(4096), dim3(256), 0, stream>>>(Wout, Woutb, 16384000 / 4);
    cvt_bf16_kernel<<<dim3(192),  dim3(256), 0, stream>>>(Wih0, Wih0b, 196608 / 4);
    cvt_bf16_kernel<<<dim3(768),  dim3(256), 0, stream>>>(Wih1, Wih1b, 786432 / 4);
    hipMemsetAsync(cntp, 0, 8, stream);  // zero both barrier counters

    // encoder path
    embed_kernel<<<dim3(32), dim3(128), 0, stream>>>(tok, table, embb, vf);
    encoder_kernel<<<dim3(32), dim3(256), 0, stream>>>(vf, Wm, bm_, Wv, bv_, noise, Wl2r, bl2r,
                                                       lW1, lb1, lW2, lb2, lW3, lb3,
                                                       sW1, sb1, sW2, sb2, sW3, sb3,
                                                       o_mean, o_std, o_z, o_logp, o_sas, state);

    // GRU layer 0
    gemm_bt_kernel<<<dim3(12, 16), dim3(256), 0, stream>>>(embb, Wih0b, bih0, xW, 2048, 1536, 128);
    gru_scan_mfma_kernel<<<dim3(NWG_SCAN), dim3(384), 0, stream>>>(
        xW, Whh0, bhh0, state, lens, hbuf, out0b, cntp);
    // GRU layer 1
    gemm_bt_kernel<<<dim3(12, 16), dim3(256), 0, stream>>>(out0b, Wih1b, bih1, xW, 2048, 1536, 512);
    gru_scan_mfma_kernel<<<dim3(NWG_SCAN), dim3(384), 0, stream>>>(
        xW, Whh1, bhh1, state + 16384, lens, hbuf, out1b, cntp + 1);

    // output projection (B,S,V)
    gemm_bt_kernel<<<dim3(250, 16), dim3(256), 0, stream>>>(out1b, Woutb, bout, out, 2048, 32000, 512);
}

// Round 5
// 1177.629 us; speedup vs baseline: 2.9076x; 1.0922x over previous
//
#include <hip/hip_runtime.h>

// Frag2Mol: embed -> encoder(VAE) -> 2x GRU(scan over T=64) -> vocab GEMM.
// Sizes: B=32 S=64 V=32000 E=128 H=512 L=2 LAT=64.
// r5: scan latency-chain attack: 16 WGs (d-slice 32, 96KB Whh f16 in LDS),
//     single poller/WG, xW register-prefetch overlapped with publish drain,
//     outb stores moved off the pre-arrive vmcnt(0). r4 was 8.5us/step
//     (serial RTT chain), mechanism-independent (r2 fence == r4 atomics).

typedef __attribute__((ext_vector_type(8))) short bf16x8_t;
typedef __attribute__((ext_vector_type(8))) unsigned short u16x8_t;
typedef __attribute__((ext_vector_type(4))) float f32x4_t;
typedef __attribute__((ext_vector_type(8))) _Float16 f16x8_t;
typedef __attribute__((ext_vector_type(2))) unsigned long long ullx2_t;

#define AS_AGENT __HIP_MEMORY_SCOPE_AGENT

static __device__ __forceinline__ unsigned short f2bf(float f) {
    unsigned int u = __float_as_uint(f);
    u += 0x7fffu + ((u >> 16) & 1u);
    return (unsigned short)(u >> 16);
}
static __device__ __forceinline__ unsigned short f2h(float f) {
    _Float16 h = (_Float16)f;
    return __builtin_bit_cast(unsigned short, h);
}
static __device__ __forceinline__ float sigmoidf_(float x) {
    return 1.f / (1.f + __expf(-x));
}

// ---------------- f32 -> bf16 convert (n multiple of 4) ----------------
__global__ __launch_bounds__(256) void cvt_bf16_kernel(const float* __restrict__ in,
                                                       unsigned short* __restrict__ out, int n4) {
    int stride = gridDim.x * 256;
    for (int i = blockIdx.x * 256 + threadIdx.x; i < n4; i += stride) {
        float4 v = reinterpret_cast<const float4*>(in)[i];
        ushort4 o;
        o.x = f2bf(v.x); o.y = f2bf(v.y); o.z = f2bf(v.z); o.w = f2bf(v.w);
        reinterpret_cast<ushort4*>(out)[i] = o;
    }
}

// ---------------- embedding + masked sum ----------------
__global__ __launch_bounds__(128) void embed_kernel(const int* __restrict__ tok,
                                                    const float* __restrict__ table,
                                                    unsigned short* __restrict__ embb,
                                                    float* __restrict__ vf) {
    const int b = blockIdx.x, e = threadIdx.x;
    float acc = 0.f;
    for (int s = 0; s < 64; ++s) {
        int id = tok[b * 64 + s];
        float v = table[(size_t)id * 128 + e];
        embb[(size_t)(b * 64 + s) * 128 + e] = f2bf(v);
        if (id > 2) acc += v;
    }
    vf[b * 128 + e] = acc;
}

// ---------------- encoder: mean/std/z, state = z@Wl2r^T, 2 MLPs ----------------
__global__ __launch_bounds__(256) void encoder_kernel(
    const float* __restrict__ vf,
    const float* __restrict__ Wm, const float* __restrict__ bm,
    const float* __restrict__ Wv, const float* __restrict__ bv,
    const float* __restrict__ noise,
    const float* __restrict__ Wl2r, const float* __restrict__ bl2r,
    const float* __restrict__ lW1, const float* __restrict__ lb1,
    const float* __restrict__ lW2, const float* __restrict__ lb2,
    const float* __restrict__ lW3, const float* __restrict__ lb3,
    const float* __restrict__ sW1, const float* __restrict__ sb1,
    const float* __restrict__ sW2, const float* __restrict__ sb2,
    const float* __restrict__ sW3, const float* __restrict__ sb3,
    float* __restrict__ o_mean, float* __restrict__ o_std, float* __restrict__ o_z,
    float* __restrict__ o_logp, float* __restrict__ o_sas,
    float* __restrict__ state)
{
    const int b = blockIdx.x, tid = threadIdx.x;
    __shared__ float v_[128], mn[64], sd[64], zz[2][64], hh1[200], hh2[100];
    if (tid < 128) v_[tid] = vf[b * 128 + tid];
    __syncthreads();
    if (tid < 128) {
        int j = tid & 63;
        bool isv = tid >= 64;
        const float* W = (isv ? Wv : Wm) + j * 128;
        float a = isv ? bv[j] : bm[j];
#pragma unroll 4
        for (int k = 0; k < 128; ++k) a = fmaf(v_[k], W[k], a);
        if (!isv) { mn[j] = a; o_mean[b * 64 + j] = a; }
        else      { float s = __expf(0.5f * a); sd[j] = s; o_std[b * 64 + j] = s; }
    }
    __syncthreads();
    if (tid < 128) {
        int l = tid >> 6, j = tid & 63;
        float zv = fmaf(noise[(l * 32 + b) * 64 + j], sd[j], mn[j]);
        zz[l][j] = zv;
        o_z[(l * 32 + b) * 64 + j] = zv;
    }
    __syncthreads();
#pragma unroll
    for (int p = 0; p < 4; ++p) {
        int tt = p * 256 + tid;
        int l = tt >> 9, hd = tt & 511;
        const float* W = Wl2r + hd * 64;
        float a = bl2r[hd];
#pragma unroll 4
        for (int k = 0; k < 64; ++k) a = fmaf(zz[l][k], W[k], a);
        state[(size_t)(l * 32 + b) * 512 + hd] = a;
    }
    if (tid < 200) {
        const float* W = lW1 + tid * 64;
        float a = lb1[tid];
        for (int k = 0; k < 64; ++k) a = fmaf(mn[k], W[k], a);
        hh1[tid] = fmaxf(a, 0.f);
    }
    __syncthreads();
    if (tid < 100) {
        const float* W = lW2 + tid * 200;
        float a = lb2[tid];
        for (int k = 0; k < 200; ++k) a = fmaf(hh1[k], W[k], a);
        hh2[tid] = fmaxf(a, 0.f);
    }
    __syncthreads();
    if (tid == 0) {
        float a = lb3[0];
        for (int k = 0; k < 100; ++k) a = fmaf(hh2[k], lW3[k], a);
        o_logp[b] = a;
    }
    __syncthreads();
    if (tid < 200) {
        const float* W = sW1 + tid * 64;
        float a = sb1[tid];
        for (int k = 0; k < 64; ++k) a = fmaf(mn[k], W[k], a);
        hh1[tid] = fmaxf(a, 0.f);
    }
    __syncthreads();
    if (tid < 100) {
        const float* W = sW2 + tid * 200;
        float a = sb2[tid];
        for (int k = 0; k < 200; ++k) a = fmaf(hh1[k], W[k], a);
        hh2[tid] = fmaxf(a, 0.f);
    }
    __syncthreads();
    if (tid == 0) {
        float a = sb3[0];
        for (int k = 0; k < 100; ++k) a = fmaf(hh2[k], sW3[k], a);
        o_sas[b] = a;
    }
}

// ---------------- bf16 MFMA GEMM: C(MxN,f32) = A(MxK) * B(NxK)^T + bias ----------------
__global__ __launch_bounds__(256) void gemm_bt_kernel(
    const unsigned short* __restrict__ A,
    const unsigned short* __restrict__ B,
    const float* __restrict__ bias,
    float* __restrict__ C,
    int M, int N, int K)
{
    __shared__ unsigned short lA[128 * 64];
    __shared__ unsigned short lB[128 * 64];
    const int tid = threadIdx.x;
    const int lane = tid & 63;
    const int wave = tid >> 6;
    const int wm = wave >> 1, wn = wave & 1;
    const int m0 = blockIdx.y * 128, n0 = blockIdx.x * 128;

    f32x4_t acc[4][4];
#pragma unroll
    for (int i = 0; i < 4; ++i)
#pragma unroll
        for (int j = 0; j < 4; ++j) acc[i][j] = (f32x4_t){0.f, 0.f, 0.f, 0.f};

    for (int kt = 0; kt < K; kt += 64) {
#pragma unroll
        for (int p = 0; p < 4; ++p) {
            int g = p * 256 + tid;
            int row = g >> 3, c8 = g & 7;
            int dst = row * 64 + ((c8 ^ (row & 7)) << 3);
            *(u16x8_t*)&lA[dst] = *(const u16x8_t*)(A + (size_t)(m0 + row) * K + kt + (c8 << 3));
            *(u16x8_t*)&lB[dst] = *(const u16x8_t*)(B + (size_t)(n0 + row) * K + kt + (c8 << 3));
        }
        __syncthreads();
#pragma unroll
        for (int kc = 0; kc < 2; ++kc) {
            bf16x8_t af[4], bfr[4];
            int c8 = kc * 4 + (lane >> 4);
#pragma unroll
            for (int i = 0; i < 4; ++i) {
                int ra = wm * 64 + i * 16 + (lane & 15);
                af[i] = *(const bf16x8_t*)&lA[ra * 64 + ((c8 ^ (ra & 7)) << 3)];
                int rb = wn * 64 + i * 16 + (lane & 15);
                bfr[i] = *(const bf16x8_t*)&lB[rb * 64 + ((c8 ^ (rb & 7)) << 3)];
            }
#pragma unroll
            for (int i = 0; i < 4; ++i)
#pragma unroll
                for (int j = 0; j < 4; ++j)
                    acc[i][j] = __builtin_amdgcn_mfma_f32_16x16x32_bf16(af[i], bfr[j], acc[i][j], 0, 0, 0);
        }
        __syncthreads();
    }
    const int lm = (lane >> 4) * 4, ln = lane & 15;
#pragma unroll
    for (int i = 0; i < 4; ++i) {
        int gm = m0 + wm * 64 + i * 16 + lm;
#pragma unroll
        for (int j = 0; j < 4; ++j) {
            int gn = n0 + wn * 64 + j * 16 + ln;
            float bb = bias ? bias[gn] : 0.f;
#pragma unroll
            for (int r = 0; r < 4; ++r)
                C[(size_t)(gm + r) * N + gn] = acc[i][j][r] + bb;
        }
    }
}

// ---------------- GRU scan, MFMA + fine-grained atomic barrier, 16 WGs ----------------
// 16 WGs (one per 32-d slice), 512 threads = 8 waves. Waves 0..5 do MFMA
// ((gate, M-tile), 2 N-tiles each); all 512 threads do the gate update
// (one (b, d-pair) each). Whh slice (96 rows x 512 f16 = 96 KB) in LDS.
// h exchanged via agent-scope relaxed atomics, double-buffered in hbuf.
// Chain opts: tid0-only poll, xW reg-prefetch, outb stores after arrive.
#define NWG_SCAN 16

__global__ __launch_bounds__(512) void gru_scan_mfma_kernel(
    const float* __restrict__ xW,      // 2048 x 1536 (x@Wih^T + bih)
    const float* __restrict__ Whh,     // 1536 x 512 f32
    const float* __restrict__ bhh,     // 1536
    const float* __restrict__ h0,      // 32 x 512 f32
    const int* __restrict__ lengths,   // 32
    unsigned short* __restrict__ hbuf, // 2 x 32 x 512 f16 (double buffer)
    unsigned short* __restrict__ outb, // 2048 x 512 bf16 (masked rows = 0)
    int* __restrict__ cnt)             // barrier counter (zeroed before launch)
{
    __shared__ unsigned short Wl[3 * 2 * 16 * 64 * 8];  // 96 KB f16 fragments
    __shared__ float Csm[3][32][34];                    // [gate][b][d-local], 8B-aligned rows
    const int tid = threadIdx.x;
    const int d0 = blockIdx.x * 32;
    const int lane = tid & 63;
    const int wave = tid >> 6;          // 0..7
    const int gate = wave >> 1;         // 0=r 1=z 2=n (waves 0..5)
    const int mt = wave & 1;            // M-tile (batches 0-15 / 16-31)

    // ---- preload Whh slice into LDS as f16 B-fragments (once) ----
    // frag id: ((gate*2+nt)*16 + kk)*64 + lane ; B-row = gate*512 + d0 + nt*16
    // + (lane&15); k = kk*32 + (lane>>4)*8 .. +8
    for (int idx = tid; idx < 3 * 2 * 16 * 64; idx += 512) {
        int ln = idx & 63;
        int kk = (idx >> 6) & 15;
        int nt = (idx >> 10) & 1;
        int g_ = idx >> 11;
        int grow = g_ * 512 + d0 + nt * 16 + (ln & 15);
        int k = kk * 32 + ((ln >> 4) << 3);
        const float* src = Whh + (size_t)grow * 512 + k;
        f16x8_t v;
#pragma unroll
        for (int j = 0; j < 8; ++j) v[j] = (_Float16)src[j];
        *(f16x8_t*)&Wl[idx << 3] = v;
    }

    // ---- update-phase ownership: thread owns (b = tid>>4, d-pair dpl = 2*(tid&15)) ----
    const int ub = tid >> 4;            // 0..31
    const int dpl = (tid & 15) * 2;     // 0..30 (local d)
    const int ud = d0 + dpl;            // global d
    unsigned int* __restrict__ hb32 = (unsigned int*)hbuf;
    unsigned int* __restrict__ ob32 = (unsigned int*)outb;
    float h_lo = h0[(size_t)ub * 512 + ud];
    float h_hi = h0[(size_t)ub * 512 + ud + 1];
    const float br_lo = bhh[ud],        br_hi = bhh[ud + 1];
    const float bz_lo = bhh[512 + ud],  bz_hi = bhh[512 + ud + 1];
    const float bn_lo = bhh[1024 + ud], bn_hi = bhh[1024 + ud + 1];
    const int lenb = lengths[ub];

    // initial publish + xW prefetch for t=0
    {
        unsigned int hw = (unsigned int)f2h(h_lo) | ((unsigned int)f2h(h_hi) << 16);
        __hip_atomic_store(&hb32[ub * 256 + (ud >> 1)], hw, __ATOMIC_RELAXED, AS_AGENT);
    }
    const float* xrow = xW + (size_t)(ub * 64) * 1536 + ud;
    float2 px_r = *(const float2*)(xrow);
    float2 px_z = *(const float2*)(xrow + 512);
    float2 px_n = *(const float2*)(xrow + 1024);
    asm volatile("s_waitcnt vmcnt(0)" ::: "memory");
    __syncthreads();
    if (tid == 0) {
        __hip_atomic_fetch_add(cnt, 1, __ATOMIC_RELAXED, AS_AGENT);
        while (__hip_atomic_load(cnt, __ATOMIC_RELAXED, AS_AGENT) < NWG_SCAN)
            __builtin_amdgcn_s_sleep(1);
    }
    __syncthreads();

    // ---- MFMA-phase constants ----
    const unsigned long long* __restrict__ hb64 = (const unsigned long long*)hbuf;
    const int brow = mt * 16 + (lane & 15);   // A-row (batch)
    const int ko = lane >> 4;                 // k-subchunk 0..3

    for (int t = 0; t < 64; ++t) {
        // ---- hW = h @ Whh^T : waves 0..5, two 16x16 N-tiles per wave ----
        if (wave < 6) {
            const unsigned long long* hb = hb64 + (size_t)(t & 1) * 4096 + (size_t)brow * 128;
            f32x4_t acc0 = (f32x4_t){0.f, 0.f, 0.f, 0.f};
            f32x4_t acc1 = (f32x4_t){0.f, 0.f, 0.f, 0.f};
#pragma unroll
            for (int kk = 0; kk < 16; ++kk) {
                int j0 = kk * 8 + ko * 2;
                unsigned long long lo = __hip_atomic_load(&hb[j0], __ATOMIC_RELAXED, AS_AGENT);
                unsigned long long hi = __hip_atomic_load(&hb[j0 + 1], __ATOMIC_RELAXED, AS_AGENT);
                ullx2_t u; u[0] = lo; u[1] = hi;
                f16x8_t af = __builtin_bit_cast(f16x8_t, u);
                f16x8_t bf0 = *(const f16x8_t*)&Wl[(((gate * 2 + 0) * 16 + kk) * 64 + lane) << 3];
                f16x8_t bf1 = *(const f16x8_t*)&Wl[(((gate * 2 + 1) * 16 + kk) * 64 + lane) << 3];
                acc0 = __builtin_amdgcn_mfma_f32_16x16x32_f16(af, bf0, acc0, 0, 0, 0);
                acc1 = __builtin_amdgcn_mfma_f32_16x16x32_f16(af, bf1, acc1, 0, 0, 0);
            }
            const int crow = mt * 16 + ((lane >> 4) << 2), ccol = lane & 15;
#pragma unroll
            for (int r = 0; r < 4; ++r) {
                Csm[gate][crow + r][ccol] = acc0[r];
                Csm[gate][crow + r][16 + ccol] = acc1[r];
            }
        }
        __syncthreads();

        // ---- gate update (prefetched xW) ----
        unsigned int oword;
        if (t < lenb) {
            float hr_lo = Csm[0][ub][dpl], hr_hi = Csm[0][ub][dpl + 1];
            float hz_lo = Csm[1][ub][dpl], hz_hi = Csm[1][ub][dpl + 1];
            float hn_lo = Csm[2][ub][dpl], hn_hi = Csm[2][ub][dpl + 1];
            float r0 = sigmoidf_(px_r.x + hr_lo + br_lo);
            float r1 = sigmoidf_(px_r.y + hr_hi + br_hi);
            float u0 = sigmoidf_(px_z.x + hz_lo + bz_lo);
            float u1 = sigmoidf_(px_z.y + hz_hi + bz_hi);
            float n0 = tanhf(px_n.x + r0 * (hn_lo + bn_lo));
            float n1 = tanhf(px_n.y + r1 * (hn_hi + bn_hi));
            h_lo = (1.f - u0) * n0 + u0 * h_lo;
            h_hi = (1.f - u1) * n1 + u1 * h_hi;
            oword = (unsigned int)f2bf(h_lo) | ((unsigned int)f2bf(h_hi) << 16);
        } else {
            oword = 0u;
        }
        // publish h (small, on critical chain)
        {
            unsigned int hw = (unsigned int)f2h(h_lo) | ((unsigned int)f2h(h_hi) << 16);
            __hip_atomic_store(&hb32[((t + 1) & 1) * 8192 + ub * 256 + (ud >> 1)],
                               hw, __ATOMIC_RELAXED, AS_AGENT);
        }
        // prefetch xW for t+1 (overlaps publish drain)
        {
            int tn = t + 1 < 64 ? t + 1 : 63;
            const float* xp = xW + (size_t)(ub * 64 + tn) * 1536 + ud;
            px_r = *(const float2*)(xp);
            px_z = *(const float2*)(xp + 512);
            px_n = *(const float2*)(xp + 1024);
        }
        asm volatile("s_waitcnt vmcnt(0)" ::: "memory");
        __syncthreads();   // Csm reads done; h publish drained

        if (t < 63) {
            if (tid == 0) __hip_atomic_fetch_add(cnt, 1, __ATOMIC_RELAXED, AS_AGENT);
            // outb store off the critical chain (completes during poll)
            ob32[(size_t)(ub * 64 + t) * 256 + (ud >> 1)] = oword;
            if (tid == 0) {
                const int tgt = NWG_SCAN * (t + 2);
                while (__hip_atomic_load(cnt, __ATOMIC_RELAXED, AS_AGENT) < tgt)
                    __builtin_amdgcn_s_sleep(1);
            }
            __syncthreads();
        } else {
            ob32[(size_t)(ub * 64 + t) * 256 + (ud >> 1)] = oword;
        }
    }
}

extern "C" void kernel_launch(void* const* d_in, const int* in_sizes, int n_in,
                              void* d_out, int out_size, void* d_ws, size_t ws_size,
                              hipStream_t stream) {
    const int*   tok    = (const int*)d_in[0];
    const int*   lens   = (const int*)d_in[1];
    const float* noise  = (const float*)d_in[2];
    const float* table  = (const float*)d_in[3];
    const float* Wm     = (const float*)d_in[4];
    const float* bm_    = (const float*)d_in[5];
    const float* Wv     = (const float*)d_in[6];
    const float* bv_    = (const float*)d_in[7];
    const float* Wl2r   = (const float*)d_in[8];
    const float* bl2r   = (const float*)d_in[9];
    const float* Wih0   = (const float*)d_in[10];
    const float* Whh0   = (const float*)d_in[11];
    const float* bih0   = (const float*)d_in[12];
    const float* bhh0   = (const float*)d_in[13];
    const float* Wih1   = (const float*)d_in[14];
    const float* Whh1   = (const float*)d_in[15];
    const float* bih1   = (const float*)d_in[16];
    const float* bhh1   = (const float*)d_in[17];
    const float* Wout   = (const float*)d_in[18];
    const float* bout   = (const float*)d_in[19];
    const float* lW1 = (const float*)d_in[20]; const float* lb1 = (const float*)d_in[21];
    const float* lW2 = (const float*)d_in[22]; const float* lb2 = (const float*)d_in[23];
    const float* lW3 = (const float*)d_in[24]; const float* lb3 = (const float*)d_in[25];
    const float* sW1 = (const float*)d_in[26]; const float* sb1 = (const float*)d_in[27];
    const float* sW2 = (const float*)d_in[28]; const float* sb2 = (const float*)d_in[29];
    const float* sW3 = (const float*)d_in[30]; const float* sb3 = (const float*)d_in[31];

    float* out    = (float*)d_out;           // (B,S,V) = 2048 x 32000
    float* o_mean = out + 65536000;
    float* o_std  = o_mean + 2048;
    float* o_z    = o_std + 2048;
    float* o_logp = o_z + 4096;
    float* o_sas  = o_logp + 32;

    char* ws = (char*)d_ws;
    unsigned short* Woutb = (unsigned short*)ws;  ws += 32768000;  // 32000x512 bf16
    unsigned short* Wih0b = (unsigned short*)ws;  ws += 393216;    // 1536x128 bf16
    unsigned short* Wih1b = (unsigned short*)ws;  ws += 1572864;   // 1536x512 bf16
    unsigned short* embb  = (unsigned short*)ws;  ws += 524288;    // 2048x128 bf16
    float*          vf    = (float*)ws;           ws += 16384;     // 32x128
    float*          state = (float*)ws;           ws += 131072;    // 2x32x512
    float*          xW    = (float*)ws;           ws += 12582912;  // 2048x1536 f32 (reused)
    unsigned short* out0b = (unsigned short*)ws;  ws += 2097152;   // 2048x512 bf16
    unsigned short* out1b = (unsigned short*)ws;  ws += 2097152;
    unsigned short* hbuf  = (unsigned short*)ws;  ws += 65536;     // 2x32x512 f16
    int*            cntp  = (int*)ws;             ws += 256;       // 2 barrier counters

    // weight preprocessing (input-independent)
    cvt_bf16_kernel<<<dim3(4096), dim3(256), 0, stream>>>(Wout, Woutb, 16384000 / 4);
    cvt_bf16_kernel<<<dim3(192),  dim3(256), 0, stream>>>(Wih0, Wih0b, 196608 / 4);
    cvt_bf16_kernel<<<dim3(768),  dim3(256), 0, stream>>>(Wih1, Wih1b, 786432 / 4);
    hipMemsetAsync(cntp, 0, 8, stream);  // zero both barrier counters

    // encoder path
    embed_kernel<<<dim3(32), dim3(128), 0, stream>>>(tok, table, embb, vf);
    encoder_kernel<<<dim3(32), dim3(256), 0, stream>>>(vf, Wm, bm_, Wv, bv_, noise, Wl2r, bl2r,
                                                       lW1, lb1, lW2, lb2, lW3, lb3,
                                                       sW1, sb1, sW2, sb2, sW3, sb3,
                                                       o_mean, o_std, o_z, o_logp, o_sas, state);

    // GRU layer 0
    gemm_bt_kernel<<<dim3(12, 16), dim3(256), 0, stream>>>(embb, Wih0b, bih0, xW, 2048, 1536, 128);
    gru_scan_mfma_kernel<<<dim3(NWG_SCAN), dim3(512), 0, stream>>>(
        xW, Whh0, bhh0, state, lens, hbuf, out0b, cntp);
    // GRU layer 1
    gemm_bt_kernel<<<dim3(12, 16), dim3(256), 0, stream>>>(out0b, Wih1b, bih1, xW, 2048, 1536, 512);
    gru_scan_mfma_kernel<<<dim3(NWG_SCAN), dim3(512), 0, stream>>>(
        xW, Whh1, bhh1, state + 16384, lens, hbuf, out1b, cntp + 1);

    // output projection (B,S,V)
    gemm_bt_kernel<<<dim3(250, 16), dim3(256), 0, stream>>>(out1b, Woutb, bout, out, 2048, 32000, 512);
}

// Round 6
// 643.284 us; speedup vs baseline: 5.3228x; 1.8307x over previous
//
#include <hip/hip_runtime.h>

// Frag2Mol: embed -> encoder(VAE) -> 2x GRU(scan over T=64) -> vocab GEMM.
// Sizes: B=32 S=64 V=32000 E=128 H=512 L=2 LAT=64.
// r6: scan h-exchange rebuilt: per-WG gather-once (wide sc0sc1 bypass loads
//     -> swizzled LDS stage) replaces per-wave scattered 8B atomic loads
//     (196K/step); per-WG epoch flags (bypass store + parallel poll) replace
//     the atomicAdd counter. r5 was 7.5us/step, mechanism-invariant.

typedef __attribute__((ext_vector_type(8))) short bf16x8_t;
typedef __attribute__((ext_vector_type(8))) unsigned short u16x8_t;
typedef __attribute__((ext_vector_type(4))) float f32x4_t;
typedef __attribute__((ext_vector_type(8))) _Float16 f16x8_t;
typedef __attribute__((ext_vector_type(4))) unsigned int u32x4_t;

#define AS_AGENT __HIP_MEMORY_SCOPE_AGENT

static __device__ __forceinline__ unsigned short f2bf(float f) {
    unsigned int u = __float_as_uint(f);
    u += 0x7fffu + ((u >> 16) & 1u);
    return (unsigned short)(u >> 16);
}
static __device__ __forceinline__ unsigned short f2h(float f) {
    _Float16 h = (_Float16)f;
    return __builtin_bit_cast(unsigned short, h);
}
static __device__ __forceinline__ float sigmoidf_(float x) {
    return 1.f / (1.f + __expf(-x));
}

// ---------------- f32 -> bf16 convert (n multiple of 4) ----------------
__global__ __launch_bounds__(256) void cvt_bf16_kernel(const float* __restrict__ in,
                                                       unsigned short* __restrict__ out, int n4) {
    int stride = gridDim.x * 256;
    for (int i = blockIdx.x * 256 + threadIdx.x; i < n4; i += stride) {
        float4 v = reinterpret_cast<const float4*>(in)[i];
        ushort4 o;
        o.x = f2bf(v.x); o.y = f2bf(v.y); o.z = f2bf(v.z); o.w = f2bf(v.w);
        reinterpret_cast<ushort4*>(out)[i] = o;
    }
}

// ---------------- embedding + masked sum ----------------
__global__ __launch_bounds__(128) void embed_kernel(const int* __restrict__ tok,
                                                    const float* __restrict__ table,
                                                    unsigned short* __restrict__ embb,
                                                    float* __restrict__ vf) {
    const int b = blockIdx.x, e = threadIdx.x;
    float acc = 0.f;
    for (int s = 0; s < 64; ++s) {
        int id = tok[b * 64 + s];
        float v = table[(size_t)id * 128 + e];
        embb[(size_t)(b * 64 + s) * 128 + e] = f2bf(v);
        if (id > 2) acc += v;
    }
    vf[b * 128 + e] = acc;
}

// ---------------- encoder: mean/std/z, state = z@Wl2r^T, 2 MLPs ----------------
__global__ __launch_bounds__(256) void encoder_kernel(
    const float* __restrict__ vf,
    const float* __restrict__ Wm, const float* __restrict__ bm,
    const float* __restrict__ Wv, const float* __restrict__ bv,
    const float* __restrict__ noise,
    const float* __restrict__ Wl2r, const float* __restrict__ bl2r,
    const float* __restrict__ lW1, const float* __restrict__ lb1,
    const float* __restrict__ lW2, const float* __restrict__ lb2,
    const float* __restrict__ lW3, const float* __restrict__ lb3,
    const float* __restrict__ sW1, const float* __restrict__ sb1,
    const float* __restrict__ sW2, const float* __restrict__ sb2,
    const float* __restrict__ sW3, const float* __restrict__ sb3,
    float* __restrict__ o_mean, float* __restrict__ o_std, float* __restrict__ o_z,
    float* __restrict__ o_logp, float* __restrict__ o_sas,
    float* __restrict__ state)
{
    const int b = blockIdx.x, tid = threadIdx.x;
    __shared__ float v_[128], mn[64], sd[64], zz[2][64], hh1[200], hh2[100];
    if (tid < 128) v_[tid] = vf[b * 128 + tid];
    __syncthreads();
    if (tid < 128) {
        int j = tid & 63;
        bool isv = tid >= 64;
        const float* W = (isv ? Wv : Wm) + j * 128;
        float a = isv ? bv[j] : bm[j];
#pragma unroll 4
        for (int k = 0; k < 128; ++k) a = fmaf(v_[k], W[k], a);
        if (!isv) { mn[j] = a; o_mean[b * 64 + j] = a; }
        else      { float s = __expf(0.5f * a); sd[j] = s; o_std[b * 64 + j] = s; }
    }
    __syncthreads();
    if (tid < 128) {
        int l = tid >> 6, j = tid & 63;
        float zv = fmaf(noise[(l * 32 + b) * 64 + j], sd[j], mn[j]);
        zz[l][j] = zv;
        o_z[(l * 32 + b) * 64 + j] = zv;
    }
    __syncthreads();
#pragma unroll
    for (int p = 0; p < 4; ++p) {
        int tt = p * 256 + tid;
        int l = tt >> 9, hd = tt & 511;
        const float* W = Wl2r + hd * 64;
        float a = bl2r[hd];
#pragma unroll 4
        for (int k = 0; k < 64; ++k) a = fmaf(zz[l][k], W[k], a);
        state[(size_t)(l * 32 + b) * 512 + hd] = a;
    }
    if (tid < 200) {
        const float* W = lW1 + tid * 64;
        float a = lb1[tid];
        for (int k = 0; k < 64; ++k) a = fmaf(mn[k], W[k], a);
        hh1[tid] = fmaxf(a, 0.f);
    }
    __syncthreads();
    if (tid < 100) {
        const float* W = lW2 + tid * 200;
        float a = lb2[tid];
        for (int k = 0; k < 200; ++k) a = fmaf(hh1[k], W[k], a);
        hh2[tid] = fmaxf(a, 0.f);
    }
    __syncthreads();
    if (tid == 0) {
        float a = lb3[0];
        for (int k = 0; k < 100; ++k) a = fmaf(hh2[k], lW3[k], a);
        o_logp[b] = a;
    }
    __syncthreads();
    if (tid < 200) {
        const float* W = sW1 + tid * 64;
        float a = sb1[tid];
        for (int k = 0; k < 64; ++k) a = fmaf(mn[k], W[k], a);
        hh1[tid] = fmaxf(a, 0.f);
    }
    __syncthreads();
    if (tid < 100) {
        const float* W = sW2 + tid * 200;
        float a = sb2[tid];
        for (int k = 0; k < 200; ++k) a = fmaf(hh1[k], W[k], a);
        hh2[tid] = fmaxf(a, 0.f);
    }
    __syncthreads();
    if (tid == 0) {
        float a = sb3[0];
        for (int k = 0; k < 100; ++k) a = fmaf(hh2[k], sW3[k], a);
        o_sas[b] = a;
    }
}

// ---------------- bf16 MFMA GEMM: C(MxN,f32) = A(MxK) * B(NxK)^T + bias ----------------
__global__ __launch_bounds__(256) void gemm_bt_kernel(
    const unsigned short* __restrict__ A,
    const unsigned short* __restrict__ B,
    const float* __restrict__ bias,
    float* __restrict__ C,
    int M, int N, int K)
{
    __shared__ unsigned short lA[128 * 64];
    __shared__ unsigned short lB[128 * 64];
    const int tid = threadIdx.x;
    const int lane = tid & 63;
    const int wave = tid >> 6;
    const int wm = wave >> 1, wn = wave & 1;
    const int m0 = blockIdx.y * 128, n0 = blockIdx.x * 128;

    f32x4_t acc[4][4];
#pragma unroll
    for (int i = 0; i < 4; ++i)
#pragma unroll
        for (int j = 0; j < 4; ++j) acc[i][j] = (f32x4_t){0.f, 0.f, 0.f, 0.f};

    for (int kt = 0; kt < K; kt += 64) {
#pragma unroll
        for (int p = 0; p < 4; ++p) {
            int g = p * 256 + tid;
            int row = g >> 3, c8 = g & 7;
            int dst = row * 64 + ((c8 ^ (row & 7)) << 3);
            *(u16x8_t*)&lA[dst] = *(const u16x8_t*)(A + (size_t)(m0 + row) * K + kt + (c8 << 3));
            *(u16x8_t*)&lB[dst] = *(const u16x8_t*)(B + (size_t)(n0 + row) * K + kt + (c8 << 3));
        }
        __syncthreads();
#pragma unroll
        for (int kc = 0; kc < 2; ++kc) {
            bf16x8_t af[4], bfr[4];
            int c8 = kc * 4 + (lane >> 4);
#pragma unroll
            for (int i = 0; i < 4; ++i) {
                int ra = wm * 64 + i * 16 + (lane & 15);
                af[i] = *(const bf16x8_t*)&lA[ra * 64 + ((c8 ^ (ra & 7)) << 3)];
                int rb = wn * 64 + i * 16 + (lane & 15);
                bfr[i] = *(const bf16x8_t*)&lB[rb * 64 + ((c8 ^ (rb & 7)) << 3)];
            }
#pragma unroll
            for (int i = 0; i < 4; ++i)
#pragma unroll
                for (int j = 0; j < 4; ++j)
                    acc[i][j] = __builtin_amdgcn_mfma_f32_16x16x32_bf16(af[i], bfr[j], acc[i][j], 0, 0, 0);
        }
        __syncthreads();
    }
    const int lm = (lane >> 4) * 4, ln = lane & 15;
#pragma unroll
    for (int i = 0; i < 4; ++i) {
        int gm = m0 + wm * 64 + i * 16 + lm;
#pragma unroll
        for (int j = 0; j < 4; ++j) {
            int gn = n0 + wn * 64 + j * 16 + ln;
            float bb = bias ? bias[gn] : 0.f;
#pragma unroll
            for (int r = 0; r < 4; ++r)
                C[(size_t)(gm + r) * N + gn] = acc[i][j][r] + bb;
        }
    }
}

// ---------------- GRU scan, MFMA + gather-once LDS + flag rendezvous ----------------
// 16 WGs (one per 32-d slice), 512 threads = 8 waves. Per step: each WG
// gathers the full h state (32x512 f16 = 32 KB) ONCE via wide sc0sc1 bypass
// loads into a bank-swizzled LDS stage; waves 0..5 run MFMA from LDS.
// Rendezvous: per-WG epoch flag (128B stride), bypass store after publish
// drain; wave-0 polls all 16 flags in parallel lanes.
#define NWG_SCAN 16

__global__ __launch_bounds__(512) void gru_scan_mfma_kernel(
    const float* __restrict__ xW,      // 2048 x 1536 (x@Wih^T + bih)
    const float* __restrict__ Whh,     // 1536 x 512 f32
    const float* __restrict__ bhh,     // 1536
    const float* __restrict__ h0,      // 32 x 512 f32
    const int* __restrict__ lengths,   // 32
    unsigned short* __restrict__ hbuf, // 2 x 32 x 512 f16 (double buffer)
    unsigned short* __restrict__ outb, // 2048 x 512 bf16 (masked rows = 0)
    int* __restrict__ flags)           // 16 epoch flags, 32-int stride (zeroed)
{
    __shared__ unsigned short Wl[3 * 2 * 16 * 64 * 8];  // 96 KB f16 B-fragments
    __shared__ u32x4_t hstage4[2048];                   // 32 KB h stage (swizzled)
    __shared__ float Csm[3][32][34];                    // [gate][b][d-local]
    const int tid = threadIdx.x;
    const int d0 = blockIdx.x * 32;
    const int lane = tid & 63;
    const int wave = tid >> 6;          // 0..7
    const int gate = wave >> 1;         // 0=r 1=z 2=n (waves 0..5)
    const int mt = wave & 1;            // M-tile (batches 0-15 / 16-31)

    // ---- preload Whh slice into LDS as f16 B-fragments (once) ----
    for (int idx = tid; idx < 3 * 2 * 16 * 64; idx += 512) {
        int ln = idx & 63;
        int kk = (idx >> 6) & 15;
        int nt = (idx >> 10) & 1;
        int g_ = idx >> 11;
        int grow = g_ * 512 + d0 + nt * 16 + (ln & 15);
        int k = kk * 32 + ((ln >> 4) << 3);
        const float* src = Whh + (size_t)grow * 512 + k;
        f16x8_t v;
#pragma unroll
        for (int j = 0; j < 8; ++j) v[j] = (_Float16)src[j];
        *(f16x8_t*)&Wl[idx << 3] = v;
    }

    // ---- update-phase ownership: thread owns (b = tid>>4, d-pair dpl = 2*(tid&15)) ----
    const int ub = tid >> 4;            // 0..31
    const int dpl = (tid & 15) * 2;     // 0..30 (local d)
    const int ud = d0 + dpl;            // global d
    unsigned int* __restrict__ hb32 = (unsigned int*)hbuf;
    unsigned int* __restrict__ ob32 = (unsigned int*)outb;
    float h_lo = h0[(size_t)ub * 512 + ud];
    float h_hi = h0[(size_t)ub * 512 + ud + 1];
    const float br_lo = bhh[ud],        br_hi = bhh[ud + 1];
    const float bz_lo = bhh[512 + ud],  bz_hi = bhh[512 + ud + 1];
    const float bn_lo = bhh[1024 + ud], bn_hi = bhh[1024 + ud + 1];
    const int lenb = lengths[ub];

    // initial publish of h0 into hbuf[0]
    {
        unsigned int hw = (unsigned int)f2h(h_lo) | ((unsigned int)f2h(h_hi) << 16);
        __hip_atomic_store(&hb32[ub * 256 + (ud >> 1)], hw, __ATOMIC_RELAXED, AS_AGENT);
    }
    asm volatile("s_waitcnt vmcnt(0)" ::: "memory");
    __syncthreads();
    if (tid == 0) __hip_atomic_store(&flags[blockIdx.x << 5], 1, __ATOMIC_RELAXED, AS_AGENT);

    // xW prefetch for t=0
    const float* xrow = xW + (size_t)(ub * 64) * 1536 + ud;
    float2 px_r = *(const float2*)(xrow);
    float2 px_z = *(const float2*)(xrow + 512);
    float2 px_n = *(const float2*)(xrow + 1024);

    for (int t = 0; t < 64; ++t) {
        // ---- poll: all WGs published h for step t ----
        if (wave == 0) {
            const int tgt = t + 1;
            for (;;) {
                int v = 0x40000000;
                if (lane < NWG_SCAN)
                    v = __hip_atomic_load(&flags[lane << 5], __ATOMIC_RELAXED, AS_AGENT);
                if (__all(v >= tgt)) break;
                __builtin_amdgcn_s_sleep(1);
            }
        }
        __syncthreads();

        // ---- gather hbuf[t&1] -> hstage (swizzled), 2048 x 16B bypass loads ----
        {
            const char* srcb = (const char*)hbuf + ((t & 1) << 15);
            u32x4_t q0, q1, q2, q3;
            asm volatile("global_load_dwordx4 %0, %1, off sc0 sc1"
                         : "=v"(q0) : "v"(srcb + ((size_t)tid << 4)) : "memory");
            asm volatile("global_load_dwordx4 %0, %1, off sc0 sc1"
                         : "=v"(q1) : "v"(srcb + ((size_t)(512 + tid) << 4)) : "memory");
            asm volatile("global_load_dwordx4 %0, %1, off sc0 sc1"
                         : "=v"(q2) : "v"(srcb + ((size_t)(1024 + tid) << 4)) : "memory");
            asm volatile("global_load_dwordx4 %0, %1, off sc0 sc1"
                         : "=v"(q3) : "v"(srcb + ((size_t)(1536 + tid) << 4)) : "memory");
            asm volatile("s_waitcnt vmcnt(0)" ::: "memory");
            int g0 = tid, g1 = 512 + tid, g2 = 1024 + tid, g3 = 1536 + tid;
            hstage4[g0 ^ ((g0 >> 6) & 7)] = q0;
            hstage4[g1 ^ ((g1 >> 6) & 7)] = q1;
            hstage4[g2 ^ ((g2 >> 6) & 7)] = q2;
            hstage4[g3 ^ ((g3 >> 6) & 7)] = q3;
        }
        __syncthreads();

        // ---- hW = h @ Whh^T : waves 0..5, two 16x16 N-tiles per wave, A from LDS ----
        if (wave < 6) {
            const int brow = mt * 16 + (lane & 15);   // A-row (batch)
            const int ko = lane >> 4;                 // k-subchunk 0..3
            f32x4_t acc0 = (f32x4_t){0.f, 0.f, 0.f, 0.f};
            f32x4_t acc1 = (f32x4_t){0.f, 0.f, 0.f, 0.f};
#pragma unroll
            for (int kk = 0; kk < 16; ++kk) {
                int g = brow * 64 + kk * 4 + ko;
                f16x8_t af = __builtin_bit_cast(f16x8_t, hstage4[g ^ (brow & 7)]);
                f16x8_t bf0 = *(const f16x8_t*)&Wl[(((gate * 2 + 0) * 16 + kk) * 64 + lane) << 3];
                f16x8_t bf1 = *(const f16x8_t*)&Wl[(((gate * 2 + 1) * 16 + kk) * 64 + lane) << 3];
                acc0 = __builtin_amdgcn_mfma_f32_16x16x32_f16(af, bf0, acc0, 0, 0, 0);
                acc1 = __builtin_amdgcn_mfma_f32_16x16x32_f16(af, bf1, acc1, 0, 0, 0);
            }
            const int crow = mt * 16 + ((lane >> 4) << 2), ccol = lane & 15;
#pragma unroll
            for (int r = 0; r < 4; ++r) {
                Csm[gate][crow + r][ccol] = acc0[r];
                Csm[gate][crow + r][16 + ccol] = acc1[r];
            }
        }
        __syncthreads();

        // ---- gate update (prefetched xW) ----
        unsigned int oword;
        if (t < lenb) {
            float hr_lo = Csm[0][ub][dpl], hr_hi = Csm[0][ub][dpl + 1];
            float hz_lo = Csm[1][ub][dpl], hz_hi = Csm[1][ub][dpl + 1];
            float hn_lo = Csm[2][ub][dpl], hn_hi = Csm[2][ub][dpl + 1];
            float r0 = sigmoidf_(px_r.x + hr_lo + br_lo);
            float r1 = sigmoidf_(px_r.y + hr_hi + br_hi);
            float u0 = sigmoidf_(px_z.x + hz_lo + bz_lo);
            float u1 = sigmoidf_(px_z.y + hz_hi + bz_hi);
            float n0 = tanhf(px_n.x + r0 * (hn_lo + bn_lo));
            float n1 = tanhf(px_n.y + r1 * (hn_hi + bn_hi));
            h_lo = (1.f - u0) * n0 + u0 * h_lo;
            h_hi = (1.f - u1) * n1 + u1 * h_hi;
            oword = (unsigned int)f2bf(h_lo) | ((unsigned int)f2bf(h_hi) << 16);
        } else {
            oword = 0u;
        }

        if (t < 63) {
            // publish h_{t+1}, drain, arrive
            unsigned int hw = (unsigned int)f2h(h_lo) | ((unsigned int)f2h(h_hi) << 16);
            __hip_atomic_store(&hb32[((t + 1) & 1) * 8192 + ub * 256 + (ud >> 1)],
                               hw, __ATOMIC_RELAXED, AS_AGENT);
            asm volatile("s_waitcnt vmcnt(0)" ::: "memory");
            __syncthreads();
            if (tid == 0)
                __hip_atomic_store(&flags[blockIdx.x << 5], t + 2, __ATOMIC_RELAXED, AS_AGENT);
            // off-chain work in the poll shadow
            ob32[(size_t)(ub * 64 + t) * 256 + (ud >> 1)] = oword;
            const float* xp = xW + (size_t)(ub * 64 + t + 1) * 1536 + ud;
            px_r = *(const float2*)(xp);
            px_z = *(const float2*)(xp + 512);
            px_n = *(const float2*)(xp + 1024);
        } else {
            ob32[(size_t)(ub * 64 + t) * 256 + (ud >> 1)] = oword;
        }
    }
}

extern "C" void kernel_launch(void* const* d_in, const int* in_sizes, int n_in,
                              void* d_out, int out_size, void* d_ws, size_t ws_size,
                              hipStream_t stream) {
    const int*   tok    = (const int*)d_in[0];
    const int*   lens   = (const int*)d_in[1];
    const float* noise  = (const float*)d_in[2];
    const float* table  = (const float*)d_in[3];
    const float* Wm     = (const float*)d_in[4];
    const float* bm_    = (const float*)d_in[5];
    const float* Wv     = (const float*)d_in[6];
    const float* bv_    = (const float*)d_in[7];
    const float* Wl2r   = (const float*)d_in[8];
    const float* bl2r   = (const float*)d_in[9];
    const float* Wih0   = (const float*)d_in[10];
    const float* Whh0   = (const float*)d_in[11];
    const float* bih0   = (const float*)d_in[12];
    const float* bhh0   = (const float*)d_in[13];
    const float* Wih1   = (const float*)d_in[14];
    const float* Whh1   = (const float*)d_in[15];
    const float* bih1   = (const float*)d_in[16];
    const float* bhh1   = (const float*)d_in[17];
    const float* Wout   = (const float*)d_in[18];
    const float* bout   = (const float*)d_in[19];
    const float* lW1 = (const float*)d_in[20]; const float* lb1 = (const float*)d_in[21];
    const float* lW2 = (const float*)d_in[22]; const float* lb2 = (const float*)d_in[23];
    const float* lW3 = (const float*)d_in[24]; const float* lb3 = (const float*)d_in[25];
    const float* sW1 = (const float*)d_in[26]; const float* sb1 = (const float*)d_in[27];
    const float* sW2 = (const float*)d_in[28]; const float* sb2 = (const float*)d_in[29];
    const float* sW3 = (const float*)d_in[30]; const float* sb3 = (const float*)d_in[31];

    float* out    = (float*)d_out;           // (B,S,V) = 2048 x 32000
    float* o_mean = out + 65536000;
    float* o_std  = o_mean + 2048;
    float* o_z    = o_std + 2048;
    float* o_logp = o_z + 4096;
    float* o_sas  = o_logp + 32;

    char* ws = (char*)d_ws;
    unsigned short* Woutb = (unsigned short*)ws;  ws += 32768000;  // 32000x512 bf16
    unsigned short* Wih0b = (unsigned short*)ws;  ws += 393216;    // 1536x128 bf16
    unsigned short* Wih1b = (unsigned short*)ws;  ws += 1572864;   // 1536x512 bf16
    unsigned short* embb  = (unsigned short*)ws;  ws += 524288;    // 2048x128 bf16
    float*          vf    = (float*)ws;           ws += 16384;     // 32x128
    float*          state = (float*)ws;           ws += 131072;    // 2x32x512
    float*          xW    = (float*)ws;           ws += 12582912;  // 2048x1536 f32 (reused)
    unsigned short* out0b = (unsigned short*)ws;  ws += 2097152;   // 2048x512 bf16
    unsigned short* out1b = (unsigned short*)ws;  ws += 2097152;
    unsigned short* hbuf  = (unsigned short*)ws;  ws += 65536;     // 2x32x512 f16
    int*            cntp  = (int*)ws;             ws += 8192;      // 2 layers x 16 flags x 128B

    // weight preprocessing (input-independent)
    cvt_bf16_kernel<<<dim3(4096), dim3(256), 0, stream>>>(Wout, Woutb, 16384000 / 4);
    cvt_bf16_kernel<<<dim3(192),  dim3(256), 0, stream>>>(Wih0, Wih0b, 196608 / 4);
    cvt_bf16_kernel<<<dim3(768),  dim3(256), 0, stream>>>(Wih1, Wih1b, 786432 / 4);
    hipMemsetAsync(cntp, 0, 4096, stream);  // zero both layers' flag blocks

    // encoder path
    embed_kernel<<<dim3(32), dim3(128), 0, stream>>>(tok, table, embb, vf);
    encoder_kernel<<<dim3(32), dim3(256), 0, stream>>>(vf, Wm, bm_, Wv, bv_, noise, Wl2r, bl2r,
                                                       lW1, lb1, lW2, lb2, lW3, lb3,
                                                       sW1, sb1, sW2, sb2, sW3, sb3,
                                                       o_mean, o_std, o_z, o_logp, o_sas, state);

    // GRU layer 0
    gemm_bt_kernel<<<dim3(12, 16), dim3(256), 0, stream>>>(embb, Wih0b, bih0, xW, 2048, 1536, 128);
    gru_scan_mfma_kernel<<<dim3(NWG_SCAN), dim3(512), 0, stream>>>(
        xW, Whh0, bhh0, state, lens, hbuf, out0b, cntp);
    // GRU layer 1
    gemm_bt_kernel<<<dim3(12, 16), dim3(256), 0, stream>>>(out0b, Wih1b, bih1, xW, 2048, 1536, 512);
    gru_scan_mfma_kernel<<<dim3(NWG_SCAN), dim3(512), 0, stream>>>(
        xW, Whh1, bhh1, state + 16384, lens, hbuf, out1b, cntp + 512);

    // output projection (B,S,V)
    gemm_bt_kernel<<<dim3(250, 16), dim3(256), 0, stream>>>(out1b, Woutb, bout, out, 2048, 32000, 512);
}

// Round 8
// 460.803 us; speedup vs baseline: 7.4306x; 1.3960x over previous
//
#include <hip/hip_runtime.h>

// Frag2Mol: embed -> encoder(VAE) -> 2x GRU(scan over T=64) -> vocab GEMM.
// Sizes: B=32 S=64 V=32000 E=128 H=512 L=2 LAT=64.
// r8: r7 (fused 2-layer pipelined GRU scan, 48 WGs, 65 rounds) with the
//     udp/dpl variable-name compile fix. Design notes in r7 header.

typedef __attribute__((ext_vector_type(8))) short bf16x8_t;
typedef __attribute__((ext_vector_type(8))) unsigned short u16x8_t;
typedef __attribute__((ext_vector_type(4))) float f32x4_t;
typedef __attribute__((ext_vector_type(8))) _Float16 f16x8_t;
typedef __attribute__((ext_vector_type(4))) unsigned int u32x4_t;

#define AS_AGENT __HIP_MEMORY_SCOPE_AGENT

static __device__ __forceinline__ unsigned short f2bf(float f) {
    unsigned int u = __float_as_uint(f);
    u += 0x7fffu + ((u >> 16) & 1u);
    return (unsigned short)(u >> 16);
}
static __device__ __forceinline__ unsigned short f2h(float f) {
    _Float16 h = (_Float16)f;
    return __builtin_bit_cast(unsigned short, h);
}
static __device__ __forceinline__ float sigmoidf_(float x) {
    return 1.f / (1.f + __expf(-x));
}

// ---------------- f32 -> bf16 convert (n multiple of 4) ----------------
__global__ __launch_bounds__(256) void cvt_bf16_kernel(const float* __restrict__ in,
                                                       unsigned short* __restrict__ out, int n4) {
    int stride = gridDim.x * 256;
    for (int i = blockIdx.x * 256 + threadIdx.x; i < n4; i += stride) {
        float4 v = reinterpret_cast<const float4*>(in)[i];
        ushort4 o;
        o.x = f2bf(v.x); o.y = f2bf(v.y); o.z = f2bf(v.z); o.w = f2bf(v.w);
        reinterpret_cast<ushort4*>(out)[i] = o;
    }
}

// ---------------- embedding + masked sum ----------------
__global__ __launch_bounds__(128) void embed_kernel(const int* __restrict__ tok,
                                                    const float* __restrict__ table,
                                                    unsigned short* __restrict__ embb,
                                                    float* __restrict__ vf) {
    const int b = blockIdx.x, e = threadIdx.x;
    float acc = 0.f;
    for (int s = 0; s < 64; ++s) {
        int id = tok[b * 64 + s];
        float v = table[(size_t)id * 128 + e];
        embb[(size_t)(b * 64 + s) * 128 + e] = f2bf(v);
        if (id > 2) acc += v;
    }
    vf[b * 128 + e] = acc;
}

// ---------------- encoder: mean/std/z, state = z@Wl2r^T, 2 MLPs ----------------
__global__ __launch_bounds__(256) void encoder_kernel(
    const float* __restrict__ vf,
    const float* __restrict__ Wm, const float* __restrict__ bm,
    const float* __restrict__ Wv, const float* __restrict__ bv,
    const float* __restrict__ noise,
    const float* __restrict__ Wl2r, const float* __restrict__ bl2r,
    const float* __restrict__ lW1, const float* __restrict__ lb1,
    const float* __restrict__ lW2, const float* __restrict__ lb2,
    const float* __restrict__ lW3, const float* __restrict__ lb3,
    const float* __restrict__ sW1, const float* __restrict__ sb1,
    const float* __restrict__ sW2, const float* __restrict__ sb2,
    const float* __restrict__ sW3, const float* __restrict__ sb3,
    float* __restrict__ o_mean, float* __restrict__ o_std, float* __restrict__ o_z,
    float* __restrict__ o_logp, float* __restrict__ o_sas,
    float* __restrict__ state)
{
    const int b = blockIdx.x, tid = threadIdx.x;
    __shared__ float v_[128], mn[64], sd[64], zz[2][64], hh1[200], hh2[100];
    if (tid < 128) v_[tid] = vf[b * 128 + tid];
    __syncthreads();
    if (tid < 128) {
        int j = tid & 63;
        bool isv = tid >= 64;
        const float* W = (isv ? Wv : Wm) + j * 128;
        float a = isv ? bv[j] : bm[j];
#pragma unroll 4
        for (int k = 0; k < 128; ++k) a = fmaf(v_[k], W[k], a);
        if (!isv) { mn[j] = a; o_mean[b * 64 + j] = a; }
        else      { float s = __expf(0.5f * a); sd[j] = s; o_std[b * 64 + j] = s; }
    }
    __syncthreads();
    if (tid < 128) {
        int l = tid >> 6, j = tid & 63;
        float zv = fmaf(noise[(l * 32 + b) * 64 + j], sd[j], mn[j]);
        zz[l][j] = zv;
        o_z[(l * 32 + b) * 64 + j] = zv;
    }
    __syncthreads();
#pragma unroll
    for (int p = 0; p < 4; ++p) {
        int tt = p * 256 + tid;
        int l = tt >> 9, hd = tt & 511;
        const float* W = Wl2r + hd * 64;
        float a = bl2r[hd];
#pragma unroll 4
        for (int k = 0; k < 64; ++k) a = fmaf(zz[l][k], W[k], a);
        state[(size_t)(l * 32 + b) * 512 + hd] = a;
    }
    if (tid < 200) {
        const float* W = lW1 + tid * 64;
        float a = lb1[tid];
        for (int k = 0; k < 64; ++k) a = fmaf(mn[k], W[k], a);
        hh1[tid] = fmaxf(a, 0.f);
    }
    __syncthreads();
    if (tid < 100) {
        const float* W = lW2 + tid * 200;
        float a = lb2[tid];
        for (int k = 0; k < 200; ++k) a = fmaf(hh1[k], W[k], a);
        hh2[tid] = fmaxf(a, 0.f);
    }
    __syncthreads();
    if (tid == 0) {
        float a = lb3[0];
        for (int k = 0; k < 100; ++k) a = fmaf(hh2[k], lW3[k], a);
        o_logp[b] = a;
    }
    __syncthreads();
    if (tid < 200) {
        const float* W = sW1 + tid * 64;
        float a = sb1[tid];
        for (int k = 0; k < 64; ++k) a = fmaf(mn[k], W[k], a);
        hh1[tid] = fmaxf(a, 0.f);
    }
    __syncthreads();
    if (tid < 100) {
        const float* W = sW2 + tid * 200;
        float a = sb2[tid];
        for (int k = 0; k < 200; ++k) a = fmaf(hh1[k], W[k], a);
        hh2[tid] = fmaxf(a, 0.f);
    }
    __syncthreads();
    if (tid == 0) {
        float a = sb3[0];
        for (int k = 0; k < 100; ++k) a = fmaf(hh2[k], sW3[k], a);
        o_sas[b] = a;
    }
}

// ---------------- bf16 MFMA GEMM: C(MxN,f32) = A(MxK) * B(NxK)^T + bias ----------------
__global__ __launch_bounds__(256) void gemm_bt_kernel(
    const unsigned short* __restrict__ A,
    const unsigned short* __restrict__ B,
    const float* __restrict__ bias,
    float* __restrict__ C,
    int M, int N, int K)
{
    __shared__ unsigned short lA[128 * 64];
    __shared__ unsigned short lB[128 * 64];
    const int tid = threadIdx.x;
    const int lane = tid & 63;
    const int wave = tid >> 6;
    const int wm = wave >> 1, wn = wave & 1;
    const int m0 = blockIdx.y * 128, n0 = blockIdx.x * 128;

    f32x4_t acc[4][4];
#pragma unroll
    for (int i = 0; i < 4; ++i)
#pragma unroll
        for (int j = 0; j < 4; ++j) acc[i][j] = (f32x4_t){0.f, 0.f, 0.f, 0.f};

    for (int kt = 0; kt < K; kt += 64) {
#pragma unroll
        for (int p = 0; p < 4; ++p) {
            int g = p * 256 + tid;
            int row = g >> 3, c8 = g & 7;
            int dst = row * 64 + ((c8 ^ (row & 7)) << 3);
            *(u16x8_t*)&lA[dst] = *(const u16x8_t*)(A + (size_t)(m0 + row) * K + kt + (c8 << 3));
            *(u16x8_t*)&lB[dst] = *(const u16x8_t*)(B + (size_t)(n0 + row) * K + kt + (c8 << 3));
        }
        __syncthreads();
#pragma unroll
        for (int kc = 0; kc < 2; ++kc) {
            bf16x8_t af[4], bfr[4];
            int c8 = kc * 4 + (lane >> 4);
#pragma unroll
            for (int i = 0; i < 4; ++i) {
                int ra = wm * 64 + i * 16 + (lane & 15);
                af[i] = *(const bf16x8_t*)&lA[ra * 64 + ((c8 ^ (ra & 7)) << 3)];
                int rb = wn * 64 + i * 16 + (lane & 15);
                bfr[i] = *(const bf16x8_t*)&lB[rb * 64 + ((c8 ^ (rb & 7)) << 3)];
            }
#pragma unroll
            for (int i = 0; i < 4; ++i)
#pragma unroll
                for (int j = 0; j < 4; ++j)
                    acc[i][j] = __builtin_amdgcn_mfma_f32_16x16x32_bf16(af[i], bfr[j], acc[i][j], 0, 0, 0);
        }
        __syncthreads();
    }
    const int lm = (lane >> 4) * 4, ln = lane & 15;
#pragma unroll
    for (int i = 0; i < 4; ++i) {
        int gm = m0 + wm * 64 + i * 16 + lm;
#pragma unroll
        for (int j = 0; j < 4; ++j) {
            int gn = n0 + wn * 64 + j * 16 + ln;
            float bb = bias ? bias[gn] : 0.f;
#pragma unroll
            for (int r = 0; r < 4; ++r)
                C[(size_t)(gm + r) * N + gn] = acc[i][j][r] + bb;
        }
    }
}

// ---------------- fused 2-layer GRU scan (pipelined, 65 rounds) ----------------
// 48 WGs: wg<16 -> L0 (d-slice 32, Whh0 96KB LDS); wg>=16 -> L1 (d-slice 16,
// [Whh1|Wih1] 96KB LDS, K=1024 in two K=512 passes over a reused 32KB stage).
// Round r: L0 runs step t=r (r<=63); L1 runs step t1=r-1 (r>=1). Exchange
// buffers (agent-scope bypass, double-buffered): h0x, h1x, o0x (f16).
// Epoch flags: L0 init=1, L1 init=2 (L1 has no round-0 work); end of round
// r(<64): flag=r+2; poll at round r waits all 48 flags >= r+1.
#define NWG_L0 16
#define NWG_TOT 48

__global__ __launch_bounds__(512) void gru_fused_kernel(
    const float* __restrict__ xW0,     // 2048 x 1536 (emb@Wih0^T + bih0)
    const float* __restrict__ Whh0, const float* __restrict__ bhh0,
    const float* __restrict__ Whh1, const float* __restrict__ Wih1,
    const float* __restrict__ bih1, const float* __restrict__ bhh1,
    const float* __restrict__ hinit,   // 2 x 32 x 512 (state)
    const int* __restrict__ lengths,   // 32
    unsigned short* __restrict__ h0x,  // 2 x 32 x 512 f16
    unsigned short* __restrict__ h1x,  // 2 x 32 x 512 f16
    unsigned short* __restrict__ o0x,  // 2 x 32 x 512 f16 (out0 exchange)
    unsigned short* __restrict__ out1b,// 2048 x 512 bf16
    int* __restrict__ flags)           // 48 flags, 32-int stride (zeroed)
{
    __shared__ unsigned short Wl[6144 * 8];   // 96 KB f16 B-fragments
    __shared__ u32x4_t hstage4[2048];         // 32 KB gather stage (swizzled)
    __shared__ float Csm[2][3][32][34];       // [plane][gate][b][d-local]
    const int tid = threadIdx.x;
    const int wg = blockIdx.x;
    const int lane = tid & 63;
    const int wave = tid >> 6;                // 0..7
    const int gate = wave >> 1;               // 0=r 1=z 2=n (waves 0..5)
    const int mt = wave & 1;                  // M-tile (batches 0-15 / 16-31)
    unsigned int* __restrict__ h0x32 = (unsigned int*)h0x;
    unsigned int* __restrict__ h1x32 = (unsigned int*)h1x;
    unsigned int* __restrict__ o0x32 = (unsigned int*)o0x;
    unsigned int* __restrict__ ob32  = (unsigned int*)out1b;

    if (wg < NWG_L0) {
        // ================= L0 role: d-slice 32 =================
        const int d0 = wg * 32;
        for (int idx = tid; idx < 6144; idx += 512) {
            int ln = idx & 63, kk = (idx >> 6) & 15, nt = (idx >> 10) & 1, g_ = idx >> 11;
            int grow = g_ * 512 + d0 + nt * 16 + (ln & 15);
            int k = kk * 32 + ((ln >> 4) << 3);
            const float* src = Whh0 + (size_t)grow * 512 + k;
            f16x8_t v;
#pragma unroll
            for (int j = 0; j < 8; ++j) v[j] = (_Float16)src[j];
            *(f16x8_t*)&Wl[idx << 3] = v;
        }
        const int ub = tid >> 4, dpl = (tid & 15) * 2, ud = d0 + dpl;
        float h_lo = hinit[(size_t)ub * 512 + ud];
        float h_hi = hinit[(size_t)ub * 512 + ud + 1];
        const float br_lo = bhh0[ud],        br_hi = bhh0[ud + 1];
        const float bz_lo = bhh0[512 + ud],  bz_hi = bhh0[512 + ud + 1];
        const float bn_lo = bhh0[1024 + ud], bn_hi = bhh0[1024 + ud + 1];
        const int lenb = lengths[ub];
        {   // init publish h0 -> h0x[0]
            unsigned int hw = (unsigned int)f2h(h_lo) | ((unsigned int)f2h(h_hi) << 16);
            __hip_atomic_store(&h0x32[ub * 256 + (ud >> 1)], hw, __ATOMIC_RELAXED, AS_AGENT);
        }
        asm volatile("s_waitcnt vmcnt(0)" ::: "memory");
        __syncthreads();
        if (tid == 0) __hip_atomic_store(&flags[wg << 5], 1, __ATOMIC_RELAXED, AS_AGENT);
        // xW0 prefetch for t=0
        const float* xrow = xW0 + (size_t)(ub * 64) * 1536 + ud;
        float2 px_r = *(const float2*)(xrow);
        float2 px_z = *(const float2*)(xrow + 512);
        float2 px_n = *(const float2*)(xrow + 1024);

        for (int r = 0; r < 64; ++r) {
            if (wave == 0) {
                const int tgt = r + 1;
                for (;;) {
                    int v = 0x40000000;
                    if (lane < NWG_TOT)
                        v = __hip_atomic_load(&flags[lane << 5], __ATOMIC_RELAXED, AS_AGENT);
                    if (__all(v >= tgt)) break;
                    __builtin_amdgcn_s_sleep(1);
                }
            }
            __syncthreads();
            // gather h0x[r&1] -> stage
            {
                const char* srcb = (const char*)h0x + ((r & 1) << 15);
                u32x4_t q0, q1, q2, q3;
                asm volatile("global_load_dwordx4 %0, %1, off sc0 sc1"
                             : "=v"(q0) : "v"(srcb + ((size_t)tid << 4)) : "memory");
                asm volatile("global_load_dwordx4 %0, %1, off sc0 sc1"
                             : "=v"(q1) : "v"(srcb + ((size_t)(512 + tid) << 4)) : "memory");
                asm volatile("global_load_dwordx4 %0, %1, off sc0 sc1"
                             : "=v"(q2) : "v"(srcb + ((size_t)(1024 + tid) << 4)) : "memory");
                asm volatile("global_load_dwordx4 %0, %1, off sc0 sc1"
                             : "=v"(q3) : "v"(srcb + ((size_t)(1536 + tid) << 4)) : "memory");
                asm volatile("s_waitcnt vmcnt(0)" ::: "memory");
                int g0 = tid, g1 = 512 + tid, g2 = 1024 + tid, g3 = 1536 + tid;
                hstage4[g0 ^ ((g0 >> 6) & 7)] = q0;
                hstage4[g1 ^ ((g1 >> 6) & 7)] = q1;
                hstage4[g2 ^ ((g2 >> 6) & 7)] = q2;
                hstage4[g3 ^ ((g3 >> 6) & 7)] = q3;
            }
            __syncthreads();
            if (wave < 6) {
                const int brow = mt * 16 + (lane & 15);
                const int ko = lane >> 4;
                f32x4_t acc0 = (f32x4_t){0.f, 0.f, 0.f, 0.f};
                f32x4_t acc1 = (f32x4_t){0.f, 0.f, 0.f, 0.f};
#pragma unroll
                for (int kk = 0; kk < 16; ++kk) {
                    int g = brow * 64 + kk * 4 + ko;
                    f16x8_t af = __builtin_bit_cast(f16x8_t, hstage4[g ^ (brow & 7)]);
                    f16x8_t bf0 = *(const f16x8_t*)&Wl[(((gate * 2 + 0) * 16 + kk) * 64 + lane) << 3];
                    f16x8_t bf1 = *(const f16x8_t*)&Wl[(((gate * 2 + 1) * 16 + kk) * 64 + lane) << 3];
                    acc0 = __builtin_amdgcn_mfma_f32_16x16x32_f16(af, bf0, acc0, 0, 0, 0);
                    acc1 = __builtin_amdgcn_mfma_f32_16x16x32_f16(af, bf1, acc1, 0, 0, 0);
                }
                const int crow = mt * 16 + ((lane >> 4) << 2), ccol = lane & 15;
#pragma unroll
                for (int rr = 0; rr < 4; ++rr) {
                    Csm[0][gate][crow + rr][ccol] = acc0[rr];
                    Csm[0][gate][crow + rr][16 + ccol] = acc1[rr];
                }
            }
            __syncthreads();
            // gate update
            unsigned int ow = 0u;
            if (r < lenb) {
                float hr_lo = Csm[0][0][ub][dpl], hr_hi = Csm[0][0][ub][dpl + 1];
                float hz_lo = Csm[0][1][ub][dpl], hz_hi = Csm[0][1][ub][dpl + 1];
                float hn_lo = Csm[0][2][ub][dpl], hn_hi = Csm[0][2][ub][dpl + 1];
                float r0 = sigmoidf_(px_r.x + hr_lo + br_lo);
                float r1 = sigmoidf_(px_r.y + hr_hi + br_hi);
                float u0 = sigmoidf_(px_z.x + hz_lo + bz_lo);
                float u1 = sigmoidf_(px_z.y + hz_hi + bz_hi);
                float n0 = tanhf(px_n.x + r0 * (hn_lo + bn_lo));
                float n1 = tanhf(px_n.y + r1 * (hn_hi + bn_hi));
                h_lo = (1.f - u0) * n0 + u0 * h_lo;
                h_hi = (1.f - u1) * n1 + u1 * h_hi;
                ow = (unsigned int)f2h(h_lo) | ((unsigned int)f2h(h_hi) << 16);
            }
            // publish h0_{t+1} and out0[t] (both on-chain: L1 reads o0x next round)
            {
                unsigned int hw = (unsigned int)f2h(h_lo) | ((unsigned int)f2h(h_hi) << 16);
                __hip_atomic_store(&h0x32[((r + 1) & 1) * 8192 + ub * 256 + (ud >> 1)],
                                   hw, __ATOMIC_RELAXED, AS_AGENT);
                __hip_atomic_store(&o0x32[(r & 1) * 8192 + ub * 256 + (ud >> 1)],
                                   ow, __ATOMIC_RELAXED, AS_AGENT);
            }
            asm volatile("s_waitcnt vmcnt(0)" ::: "memory");
            __syncthreads();
            if (tid == 0) __hip_atomic_store(&flags[wg << 5], r + 2, __ATOMIC_RELAXED, AS_AGENT);
            // off-chain: xW0 prefetch for t=r+1
            {
                int tn = r + 1 < 64 ? r + 1 : 63;
                const float* xp = xW0 + (size_t)(ub * 64 + tn) * 1536 + ud;
                px_r = *(const float2*)(xp);
                px_z = *(const float2*)(xp + 512);
                px_n = *(const float2*)(xp + 1024);
            }
        }
    } else {
        // ================= L1 role: d-slice 16, K=1024 =================
        const int lid = wg - NWG_L0;
        const int d0 = lid * 16;
        for (int idx = tid; idx < 6144; idx += 512) {
            int ln = idx & 63, kk = (idx >> 6) & 31, g_ = idx >> 11;
            int grow = g_ * 512 + d0 + (ln & 15);
            int k = (kk & 15) * 32 + ((ln >> 4) << 3);
            const float* src = (kk < 16 ? Whh1 : Wih1) + (size_t)grow * 512 + k;
            f16x8_t v;
#pragma unroll
            for (int j = 0; j < 8; ++j) v[j] = (_Float16)src[j];
            *(f16x8_t*)&Wl[idx << 3] = v;
        }
        const bool upd = (tid < 256);
        const int ub = tid >> 3, dpl = (tid & 7) * 2, ud = d0 + dpl;
        float h_lo = 0.f, h_hi = 0.f;
        float br_lo = 0.f, br_hi = 0.f, bz_lo = 0.f, bz_hi = 0.f;
        float bxn_lo = 0.f, bxn_hi = 0.f, bhn_lo = 0.f, bhn_hi = 0.f;
        int lenb = 0;
        if (upd) {
            h_lo = hinit[16384 + (size_t)ub * 512 + ud];
            h_hi = hinit[16384 + (size_t)ub * 512 + ud + 1];
            br_lo = bih1[ud] + bhh1[ud];
            br_hi = bih1[ud + 1] + bhh1[ud + 1];
            bz_lo = bih1[512 + ud] + bhh1[512 + ud];
            bz_hi = bih1[512 + ud + 1] + bhh1[512 + ud + 1];
            bxn_lo = bih1[1024 + ud];   bxn_hi = bih1[1024 + ud + 1];
            bhn_lo = bhh1[1024 + ud];   bhn_hi = bhh1[1024 + ud + 1];
            lenb = lengths[ub];
            // init publish h1 -> h1x[1] (round 1 reads parity 1)
            unsigned int hw = (unsigned int)f2h(h_lo) | ((unsigned int)f2h(h_hi) << 16);
            __hip_atomic_store(&h1x32[8192 + ub * 256 + (ud >> 1)], hw, __ATOMIC_RELAXED, AS_AGENT);
        }
        asm volatile("s_waitcnt vmcnt(0)" ::: "memory");
        __syncthreads();
        if (tid == 0) __hip_atomic_store(&flags[wg << 5], 2, __ATOMIC_RELAXED, AS_AGENT);

        for (int r = 1; r <= 64; ++r) {
            const int t1 = r - 1;
            if (wave == 0) {
                const int tgt = r + 1;
                for (;;) {
                    int v = 0x40000000;
                    if (lane < NWG_TOT)
                        v = __hip_atomic_load(&flags[lane << 5], __ATOMIC_RELAXED, AS_AGENT);
                    if (__all(v >= tgt)) break;
                    __builtin_amdgcn_s_sleep(1);
                }
            }
            __syncthreads();
            // gather: h1 first (4 loads), then out0 (4 loads); counted waits
            u32x4_t a0, a1, a2, a3, b0, b1, b2, b3;
            {
                const char* sh = (const char*)h1x + ((r & 1) << 15);
                const char* so = (const char*)o0x + (((r + 1) & 1) << 15);
                asm volatile("global_load_dwordx4 %0, %1, off sc0 sc1"
                             : "=v"(a0) : "v"(sh + ((size_t)tid << 4)) : "memory");
                asm volatile("global_load_dwordx4 %0, %1, off sc0 sc1"
                             : "=v"(a1) : "v"(sh + ((size_t)(512 + tid) << 4)) : "memory");
                asm volatile("global_load_dwordx4 %0, %1, off sc0 sc1"
                             : "=v"(a2) : "v"(sh + ((size_t)(1024 + tid) << 4)) : "memory");
                asm volatile("global_load_dwordx4 %0, %1, off sc0 sc1"
                             : "=v"(a3) : "v"(sh + ((size_t)(1536 + tid) << 4)) : "memory");
                asm volatile("global_load_dwordx4 %0, %1, off sc0 sc1"
                             : "=v"(b0) : "v"(so + ((size_t)tid << 4)) : "memory");
                asm volatile("global_load_dwordx4 %0, %1, off sc0 sc1"
                             : "=v"(b1) : "v"(so + ((size_t)(512 + tid) << 4)) : "memory");
                asm volatile("global_load_dwordx4 %0, %1, off sc0 sc1"
                             : "=v"(b2) : "v"(so + ((size_t)(1024 + tid) << 4)) : "memory");
                asm volatile("global_load_dwordx4 %0, %1, off sc0 sc1"
                             : "=v"(b3) : "v"(so + ((size_t)(1536 + tid) << 4)) : "memory");
                asm volatile("s_waitcnt vmcnt(4)" ::: "memory");  // h1 done
                int g0 = tid, g1 = 512 + tid, g2 = 1024 + tid, g3 = 1536 + tid;
                hstage4[g0 ^ ((g0 >> 6) & 7)] = a0;
                hstage4[g1 ^ ((g1 >> 6) & 7)] = a1;
                hstage4[g2 ^ ((g2 >> 6) & 7)] = a2;
                hstage4[g3 ^ ((g3 >> 6) & 7)] = a3;
            }
            __syncthreads();
            // pass 0: acc_h = h1 @ Whh1^T (one 16x16 tile per wave)
            f32x4_t acc_h = (f32x4_t){0.f, 0.f, 0.f, 0.f};
            const int brow = mt * 16 + (lane & 15);
            const int ko = lane >> 4;
            if (wave < 6) {
#pragma unroll
                for (int kk = 0; kk < 16; ++kk) {
                    int g = brow * 64 + kk * 4 + ko;
                    f16x8_t af = __builtin_bit_cast(f16x8_t, hstage4[g ^ (brow & 7)]);
                    f16x8_t bf = *(const f16x8_t*)&Wl[(((gate * 32 + kk) * 64 + lane)) << 3];
                    acc_h = __builtin_amdgcn_mfma_f32_16x16x32_f16(af, bf, acc_h, 0, 0, 0);
                }
            }
            __syncthreads();  // all reads of h1 stage done
            {
                asm volatile("s_waitcnt vmcnt(0)" ::: "memory");  // out0 done
                int g0 = tid, g1 = 512 + tid, g2 = 1024 + tid, g3 = 1536 + tid;
                hstage4[g0 ^ ((g0 >> 6) & 7)] = b0;
                hstage4[g1 ^ ((g1 >> 6) & 7)] = b1;
                hstage4[g2 ^ ((g2 >> 6) & 7)] = b2;
                hstage4[g3 ^ ((g3 >> 6) & 7)] = b3;
            }
            __syncthreads();
            // pass 1: acc_x = out0 @ Wih1^T
            if (wave < 6) {
                f32x4_t acc_x = (f32x4_t){0.f, 0.f, 0.f, 0.f};
#pragma unroll
                for (int kk = 0; kk < 16; ++kk) {
                    int g = brow * 64 + kk * 4 + ko;
                    f16x8_t af = __builtin_bit_cast(f16x8_t, hstage4[g ^ (brow & 7)]);
                    f16x8_t bf = *(const f16x8_t*)&Wl[(((gate * 32 + 16 + kk) * 64 + lane)) << 3];
                    acc_x = __builtin_amdgcn_mfma_f32_16x16x32_f16(af, bf, acc_x, 0, 0, 0);
                }
                const int crow = mt * 16 + ((lane >> 4) << 2), ccol = lane & 15;
#pragma unroll
                for (int rr = 0; rr < 4; ++rr) {
                    Csm[0][gate][crow + rr][ccol] = acc_h[rr];
                    Csm[1][gate][crow + rr][ccol] = acc_x[rr];
                }
            }
            __syncthreads();
            // gate update (n-gate: x-part and h-part kept separate)
            unsigned int ow = 0u;
            if (upd) {
                if (t1 < lenb) {
                    float hr_lo = Csm[0][0][ub][dpl], hr_hi = Csm[0][0][ub][dpl + 1];
                    float hz_lo = Csm[0][1][ub][dpl], hz_hi = Csm[0][1][ub][dpl + 1];
                    float hn_lo = Csm[0][2][ub][dpl], hn_hi = Csm[0][2][ub][dpl + 1];
                    float xr_lo = Csm[1][0][ub][dpl], xr_hi = Csm[1][0][ub][dpl + 1];
                    float xz_lo = Csm[1][1][ub][dpl], xz_hi = Csm[1][1][ub][dpl + 1];
                    float xn_lo = Csm[1][2][ub][dpl], xn_hi = Csm[1][2][ub][dpl + 1];
                    float r0 = sigmoidf_(xr_lo + hr_lo + br_lo);
                    float r1 = sigmoidf_(xr_hi + hr_hi + br_hi);
                    float u0 = sigmoidf_(xz_lo + hz_lo + bz_lo);
                    float u1 = sigmoidf_(xz_hi + hz_hi + bz_hi);
                    float n0 = tanhf(xn_lo + bxn_lo + r0 * (hn_lo + bhn_lo));
                    float n1 = tanhf(xn_hi + bxn_hi + r1 * (hn_hi + bhn_hi));
                    h_lo = (1.f - u0) * n0 + u0 * h_lo;
                    h_hi = (1.f - u1) * n1 + u1 * h_hi;
                    ow = (unsigned int)f2bf(h_lo) | ((unsigned int)f2bf(h_hi) << 16);
                }
                if (r < 64) {
                    unsigned int hw = (unsigned int)f2h(h_lo) | ((unsigned int)f2h(h_hi) << 16);
                    __hip_atomic_store(&h1x32[((r + 1) & 1) * 8192 + ub * 256 + (ud >> 1)],
                                       hw, __ATOMIC_RELAXED, AS_AGENT);
                }
            }
            if (r < 64) {
                asm volatile("s_waitcnt vmcnt(0)" ::: "memory");
                __syncthreads();
                if (tid == 0)
                    __hip_atomic_store(&flags[wg << 5], r + 2, __ATOMIC_RELAXED, AS_AGENT);
            }
            // off-chain: layer-1 output store (bf16)
            if (upd) ob32[(size_t)(ub * 64 + t1) * 256 + (ud >> 1)] = ow;
        }
    }
}

extern "C" void kernel_launch(void* const* d_in, const int* in_sizes, int n_in,
                              void* d_out, int out_size, void* d_ws, size_t ws_size,
                              hipStream_t stream) {
    const int*   tok    = (const int*)d_in[0];
    const int*   lens   = (const int*)d_in[1];
    const float* noise  = (const float*)d_in[2];
    const float* table  = (const float*)d_in[3];
    const float* Wm     = (const float*)d_in[4];
    const float* bm_    = (const float*)d_in[5];
    const float* Wv     = (const float*)d_in[6];
    const float* bv_    = (const float*)d_in[7];
    const float* Wl2r   = (const float*)d_in[8];
    const float* bl2r   = (const float*)d_in[9];
    const float* Wih0   = (const float*)d_in[10];
    const float* Whh0   = (const float*)d_in[11];
    const float* bih0   = (const float*)d_in[12];
    const float* bhh0   = (const float*)d_in[13];
    const float* Wih1   = (const float*)d_in[14];
    const float* Whh1   = (const float*)d_in[15];
    const float* bih1   = (const float*)d_in[16];
    const float* bhh1   = (const float*)d_in[17];
    const float* Wout   = (const float*)d_in[18];
    const float* bout   = (const float*)d_in[19];
    const float* lW1 = (const float*)d_in[20]; const float* lb1 = (const float*)d_in[21];
    const float* lW2 = (const float*)d_in[22]; const float* lb2 = (const float*)d_in[23];
    const float* lW3 = (const float*)d_in[24]; const float* lb3 = (const float*)d_in[25];
    const float* sW1 = (const float*)d_in[26]; const float* sb1 = (const float*)d_in[27];
    const float* sW2 = (const float*)d_in[28]; const float* sb2 = (const float*)d_in[29];
    const float* sW3 = (const float*)d_in[30]; const float* sb3 = (const float*)d_in[31];

    float* out    = (float*)d_out;           // (B,S,V) = 2048 x 32000
    float* o_mean = out + 65536000;
    float* o_std  = o_mean + 2048;
    float* o_z    = o_std + 2048;
    float* o_logp = o_z + 4096;
    float* o_sas  = o_logp + 32;

    char* ws = (char*)d_ws;
    unsigned short* Woutb = (unsigned short*)ws;  ws += 32768000;  // 32000x512 bf16
    unsigned short* Wih0b = (unsigned short*)ws;  ws += 393216;    // 1536x128 bf16
    unsigned short* embb  = (unsigned short*)ws;  ws += 524288;    // 2048x128 bf16
    float*          vf    = (float*)ws;           ws += 16384;     // 32x128
    float*          state = (float*)ws;           ws += 131072;    // 2x32x512
    float*          xW    = (float*)ws;           ws += 12582912;  // 2048x1536 f32 (layer 0)
    unsigned short* out1b = (unsigned short*)ws;  ws += 2097152;   // 2048x512 bf16
    unsigned short* h0x   = (unsigned short*)ws;  ws += 131072;    // 2x32x512 f16
    unsigned short* h1x   = (unsigned short*)ws;  ws += 131072;
    unsigned short* o0x   = (unsigned short*)ws;  ws += 131072;
    int*            flgp  = (int*)ws;             ws += 8192;      // 48 flags x 128B

    // weight preprocessing (input-independent)
    cvt_bf16_kernel<<<dim3(4096), dim3(256), 0, stream>>>(Wout, Woutb, 16384000 / 4);
    cvt_bf16_kernel<<<dim3(192),  dim3(256), 0, stream>>>(Wih0, Wih0b, 196608 / 4);
    hipMemsetAsync(flgp, 0, 8192, stream);

    // encoder path
    embed_kernel<<<dim3(32), dim3(128), 0, stream>>>(tok, table, embb, vf);
    encoder_kernel<<<dim3(32), dim3(256), 0, stream>>>(vf, Wm, bm_, Wv, bv_, noise, Wl2r, bl2r,
                                                       lW1, lb1, lW2, lb2, lW3, lb3,
                                                       sW1, sb1, sW2, sb2, sW3, sb3,
                                                       o_mean, o_std, o_z, o_logp, o_sas, state);

    // layer-0 xW GEMM (K=128), then fused 2-layer scan
    gemm_bt_kernel<<<dim3(12, 16), dim3(256), 0, stream>>>(embb, Wih0b, bih0, xW, 2048, 1536, 128);
    gru_fused_kernel<<<dim3(NWG_TOT), dim3(512), 0, stream>>>(
        xW, Whh0, bhh0, Whh1, Wih1, bih1, bhh1, state, lens, h0x, h1x, o0x, out1b, flgp);

    // output projection (B,S,V)
    gemm_bt_kernel<<<dim3(250, 16), dim3(256), 0, stream>>>(out1b, Woutb, bout, out, 2048, 32000, 512);
}

// Round 9
// 377.499 us; speedup vs baseline: 9.0704x; 1.2207x over previous
//
#include <hip/hip_runtime.h>

// Frag2Mol: embed -> encoder(VAE) -> 2x GRU(scan over T=64) -> vocab GEMM.
// Sizes: B=32 S=64 V=32000 E=128 H=512 L=2 LAT=64.
// r9: persistent 3-role kernel (256 WGs = 16 L0 + 32 L1 + 208 out-GEMM).
//     Output GEMM runs in the scan's shadow, gated per M-chunk (4 timesteps)
//     on L1 epoch flags; out1 exchanged t-major bf16 via bypass stores.
//     r8: scan 257us with 208 CUs idle; out GEMM ~120us serial after.

typedef __attribute__((ext_vector_type(8))) short bf16x8_t;
typedef __attribute__((ext_vector_type(8))) unsigned short u16x8_t;
typedef __attribute__((ext_vector_type(4))) float f32x4_t;
typedef __attribute__((ext_vector_type(8))) _Float16 f16x8_t;
typedef __attribute__((ext_vector_type(4))) unsigned int u32x4_t;

#define AS_AGENT __HIP_MEMORY_SCOPE_AGENT

static __device__ __forceinline__ unsigned short f2bf(float f) {
    unsigned int u = __float_as_uint(f);
    u += 0x7fffu + ((u >> 16) & 1u);
    return (unsigned short)(u >> 16);
}
static __device__ __forceinline__ unsigned short f2h(float f) {
    _Float16 h = (_Float16)f;
    return __builtin_bit_cast(unsigned short, h);
}
static __device__ __forceinline__ float sigmoidf_(float x) {
    return 1.f / (1.f + __expf(-x));
}

// ---------------- f32 -> bf16 convert (n multiple of 4) ----------------
__global__ __launch_bounds__(256) void cvt_bf16_kernel(const float* __restrict__ in,
                                                       unsigned short* __restrict__ out, int n4) {
    int stride = gridDim.x * 256;
    for (int i = blockIdx.x * 256 + threadIdx.x; i < n4; i += stride) {
        float4 v = reinterpret_cast<const float4*>(in)[i];
        ushort4 o;
        o.x = f2bf(v.x); o.y = f2bf(v.y); o.z = f2bf(v.z); o.w = f2bf(v.w);
        reinterpret_cast<ushort4*>(out)[i] = o;
    }
}

// ---------------- embedding + masked sum ----------------
__global__ __launch_bounds__(128) void embed_kernel(const int* __restrict__ tok,
                                                    const float* __restrict__ table,
                                                    unsigned short* __restrict__ embb,
                                                    float* __restrict__ vf) {
    const int b = blockIdx.x, e = threadIdx.x;
    float acc = 0.f;
    for (int s = 0; s < 64; ++s) {
        int id = tok[b * 64 + s];
        float v = table[(size_t)id * 128 + e];
        embb[(size_t)(b * 64 + s) * 128 + e] = f2bf(v);
        if (id > 2) acc += v;
    }
    vf[b * 128 + e] = acc;
}

// ---------------- encoder: mean/std/z, state = z@Wl2r^T, 2 MLPs ----------------
__global__ __launch_bounds__(256) void encoder_kernel(
    const float* __restrict__ vf,
    const float* __restrict__ Wm, const float* __restrict__ bm,
    const float* __restrict__ Wv, const float* __restrict__ bv,
    const float* __restrict__ noise,
    const float* __restrict__ Wl2r, const float* __restrict__ bl2r,
    const float* __restrict__ lW1, const float* __restrict__ lb1,
    const float* __restrict__ lW2, const float* __restrict__ lb2,
    const float* __restrict__ lW3, const float* __restrict__ lb3,
    const float* __restrict__ sW1, const float* __restrict__ sb1,
    const float* __restrict__ sW2, const float* __restrict__ sb2,
    const float* __restrict__ sW3, const float* __restrict__ sb3,
    float* __restrict__ o_mean, float* __restrict__ o_std, float* __restrict__ o_z,
    float* __restrict__ o_logp, float* __restrict__ o_sas,
    float* __restrict__ state)
{
    const int b = blockIdx.x, tid = threadIdx.x;
    __shared__ float v_[128], mn[64], sd[64], zz[2][64], hh1[200], hh2[100];
    if (tid < 128) v_[tid] = vf[b * 128 + tid];
    __syncthreads();
    if (tid < 128) {
        int j = tid & 63;
        bool isv = tid >= 64;
        const float* W = (isv ? Wv : Wm) + j * 128;
        float a = isv ? bv[j] : bm[j];
#pragma unroll 4
        for (int k = 0; k < 128; ++k) a = fmaf(v_[k], W[k], a);
        if (!isv) { mn[j] = a; o_mean[b * 64 + j] = a; }
        else      { float s = __expf(0.5f * a); sd[j] = s; o_std[b * 64 + j] = s; }
    }
    __syncthreads();
    if (tid < 128) {
        int l = tid >> 6, j = tid & 63;
        float zv = fmaf(noise[(l * 32 + b) * 64 + j], sd[j], mn[j]);
        zz[l][j] = zv;
        o_z[(l * 32 + b) * 64 + j] = zv;
    }
    __syncthreads();
#pragma unroll
    for (int p = 0; p < 4; ++p) {
        int tt = p * 256 + tid;
        int l = tt >> 9, hd = tt & 511;
        const float* W = Wl2r + hd * 64;
        float a = bl2r[hd];
#pragma unroll 4
        for (int k = 0; k < 64; ++k) a = fmaf(zz[l][k], W[k], a);
        state[(size_t)(l * 32 + b) * 512 + hd] = a;
    }
    if (tid < 200) {
        const float* W = lW1 + tid * 64;
        float a = lb1[tid];
        for (int k = 0; k < 64; ++k) a = fmaf(mn[k], W[k], a);
        hh1[tid] = fmaxf(a, 0.f);
    }
    __syncthreads();
    if (tid < 100) {
        const float* W = lW2 + tid * 200;
        float a = lb2[tid];
        for (int k = 0; k < 200; ++k) a = fmaf(hh1[k], W[k], a);
        hh2[tid] = fmaxf(a, 0.f);
    }
    __syncthreads();
    if (tid == 0) {
        float a = lb3[0];
        for (int k = 0; k < 100; ++k) a = fmaf(hh2[k], lW3[k], a);
        o_logp[b] = a;
    }
    __syncthreads();
    if (tid < 200) {
        const float* W = sW1 + tid * 64;
        float a = sb1[tid];
        for (int k = 0; k < 64; ++k) a = fmaf(mn[k], W[k], a);
        hh1[tid] = fmaxf(a, 0.f);
    }
    __syncthreads();
    if (tid < 100) {
        const float* W = sW2 + tid * 200;
        float a = sb2[tid];
        for (int k = 0; k < 200; ++k) a = fmaf(hh1[k], W[k], a);
        hh2[tid] = fmaxf(a, 0.f);
    }
    __syncthreads();
    if (tid == 0) {
        float a = sb3[0];
        for (int k = 0; k < 100; ++k) a = fmaf(hh2[k], sW3[k], a);
        o_sas[b] = a;
    }
}

// ---------------- bf16 MFMA GEMM (xW0 only): C = A * B^T + bias ----------------
__global__ __launch_bounds__(256) void gemm_bt_kernel(
    const unsigned short* __restrict__ A,
    const unsigned short* __restrict__ B,
    const float* __restrict__ bias,
    float* __restrict__ C,
    int M, int N, int K)
{
    __shared__ unsigned short lA[128 * 64];
    __shared__ unsigned short lB[128 * 64];
    const int tid = threadIdx.x;
    const int lane = tid & 63;
    const int wave = tid >> 6;
    const int wm = wave >> 1, wn = wave & 1;
    const int m0 = blockIdx.y * 128, n0 = blockIdx.x * 128;

    f32x4_t acc[4][4];
#pragma unroll
    for (int i = 0; i < 4; ++i)
#pragma unroll
        for (int j = 0; j < 4; ++j) acc[i][j] = (f32x4_t){0.f, 0.f, 0.f, 0.f};

    for (int kt = 0; kt < K; kt += 64) {
#pragma unroll
        for (int p = 0; p < 4; ++p) {
            int g = p * 256 + tid;
            int row = g >> 3, c8 = g & 7;
            int dst = row * 64 + ((c8 ^ (row & 7)) << 3);
            *(u16x8_t*)&lA[dst] = *(const u16x8_t*)(A + (size_t)(m0 + row) * K + kt + (c8 << 3));
            *(u16x8_t*)&lB[dst] = *(const u16x8_t*)(B + (size_t)(n0 + row) * K + kt + (c8 << 3));
        }
        __syncthreads();
#pragma unroll
        for (int kc = 0; kc < 2; ++kc) {
            bf16x8_t af[4], bfr[4];
            int c8 = kc * 4 + (lane >> 4);
#pragma unroll
            for (int i = 0; i < 4; ++i) {
                int ra = wm * 64 + i * 16 + (lane & 15);
                af[i] = *(const bf16x8_t*)&lA[ra * 64 + ((c8 ^ (ra & 7)) << 3)];
                int rb = wn * 64 + i * 16 + (lane & 15);
                bfr[i] = *(const bf16x8_t*)&lB[rb * 64 + ((c8 ^ (rb & 7)) << 3)];
            }
#pragma unroll
            for (int i = 0; i < 4; ++i)
#pragma unroll
                for (int j = 0; j < 4; ++j)
                    acc[i][j] = __builtin_amdgcn_mfma_f32_16x16x32_bf16(af[i], bfr[j], acc[i][j], 0, 0, 0);
        }
        __syncthreads();
    }
    const int lm = (lane >> 4) * 4, ln = lane & 15;
#pragma unroll
    for (int i = 0; i < 4; ++i) {
        int gm = m0 + wm * 64 + i * 16 + lm;
#pragma unroll
        for (int j = 0; j < 4; ++j) {
            int gn = n0 + wn * 64 + j * 16 + ln;
            float bb = bias ? bias[gn] : 0.f;
#pragma unroll
            for (int r = 0; r < 4; ++r)
                C[(size_t)(gm + r) * N + gn] = acc[i][j][r] + bb;
        }
    }
}

// ---------------- persistent 3-role kernel ----------------
// 256 WGs: wg<16 L0 scan; 16<=wg<48 L1 scan; wg>=48 output GEMM (shadow).
// Scan: as r8 (65 rounds, epoch flags). L1 publishes out1 t-major bf16 via
// bypass store BEFORE its drain+flag; final flag 66 after round 64.
// GEMM role: 4000 tiles (16 m x 250 n of 128x128, K=512); tile T -> WG T%208;
// gate per m-chunk on L1 flags >= 4m+6; A via bypass loads, B cached.
#define NWG_L0 16
#define NWG_TOT 48
#define NWG_ALL 256
#define NWG_GEMM 208

__global__ __launch_bounds__(512) void gru_fused_kernel(
    const float* __restrict__ xW0,     // 2048 x 1536 (emb@Wih0^T + bih0)
    const float* __restrict__ Whh0, const float* __restrict__ bhh0,
    const float* __restrict__ Whh1, const float* __restrict__ Wih1,
    const float* __restrict__ bih1, const float* __restrict__ bhh1,
    const float* __restrict__ hinit,   // 2 x 32 x 512 (state)
    const int* __restrict__ lengths,   // 32
    unsigned short* __restrict__ h0x,  // 2 x 32 x 512 f16
    unsigned short* __restrict__ h1x,  // 2 x 32 x 512 f16
    unsigned short* __restrict__ o0x,  // 2 x 32 x 512 f16 (out0 exchange)
    unsigned short* __restrict__ out1x,// 2048 x 512 bf16, t-major (row=t*32+b)
    const unsigned short* __restrict__ Woutb,  // 32000 x 512 bf16
    const float* __restrict__ bout,    // 32000
    float* __restrict__ outp,          // (B,S,V) f32
    int* __restrict__ flags)           // 48 flags, 32-int stride (zeroed)
{
    __shared__ __align__(16) char smem[157184];
    const int tid = threadIdx.x;
    const int wg = blockIdx.x;
    const int lane = tid & 63;
    const int wave = tid >> 6;                // 0..7
    unsigned int* __restrict__ h0x32 = (unsigned int*)h0x;
    unsigned int* __restrict__ h1x32 = (unsigned int*)h1x;
    unsigned int* __restrict__ o0x32 = (unsigned int*)o0x;
    unsigned int* __restrict__ o1x32 = (unsigned int*)out1x;

    if (wg >= NWG_TOT) {
        // ================= GEMM role: out = out1 @ Wout^T + bout =================
        unsigned short* lA = (unsigned short*)smem;            // 128 x 64 bf16
        unsigned short* lB = (unsigned short*)(smem + 16384);  // 128 x 64 bf16
        const int g = wg - NWG_TOT;            // 0..207
        const int wm = wave >> 2;              // 0..1 (64-row m half)
        const int wn = wave & 3;               // 0..3 (32-col n quad)
        int mPrev = -1;
        for (int T = g; T < 4000; T += NWG_GEMM) {
            const int m = T / 250, n = T % 250;
            if (m != mPrev) {
                if (wave == 0) {
                    const int tgt = 4 * m + 6;   // L1 finished t1 <= 4m+3
                    for (;;) {
                        int v = 0x40000000;
                        if (lane < 32)
                            v = __hip_atomic_load(&flags[(NWG_L0 + lane) << 5],
                                                  __ATOMIC_RELAXED, AS_AGENT);
                        if (__all(v >= tgt)) break;
                        __builtin_amdgcn_s_sleep(8);
                    }
                }
                __syncthreads();
                mPrev = m;
            }
            f32x4_t acc[4][2];
#pragma unroll
            for (int i = 0; i < 4; ++i)
#pragma unroll
                for (int j = 0; j < 2; ++j) acc[i][j] = (f32x4_t){0.f, 0.f, 0.f, 0.f};

            for (int kt = 0; kt < 512; kt += 64) {
                // stage A (bypass: out1x fresh through L3) + B (cached weights)
#pragma unroll
                for (int p = 0; p < 2; ++p) {
                    int gi = p * 512 + tid;
                    int row = gi >> 3, c8 = gi & 7;
                    int dst = row * 64 + ((c8 ^ (row & 7)) << 3);
                    u32x4_t qa, qb;
                    const char* srcA = (const char*)out1x +
                        (((size_t)(m * 128 + row)) * 512 + kt + (c8 << 3)) * 2;
                    const char* srcB = (const char*)Woutb +
                        (((size_t)(n * 128 + row)) * 512 + kt + (c8 << 3)) * 2;
                    asm volatile("global_load_dwordx4 %0, %1, off sc0 sc1"
                                 : "=v"(qa) : "v"(srcA) : "memory");
                    asm volatile("global_load_dwordx4 %0, %1, off"
                                 : "=v"(qb) : "v"(srcB) : "memory");
                    asm volatile("s_waitcnt vmcnt(0)" ::: "memory");
                    *(u32x4_t*)&lA[dst] = qa;
                    *(u32x4_t*)&lB[dst] = qb;
                }
                __syncthreads();
#pragma unroll
                for (int kc = 0; kc < 2; ++kc) {
                    bf16x8_t af[4], bfr[2];
                    int c8 = kc * 4 + (lane >> 4);
#pragma unroll
                    for (int i = 0; i < 4; ++i) {
                        int ra = wm * 64 + i * 16 + (lane & 15);
                        af[i] = *(const bf16x8_t*)&lA[ra * 64 + ((c8 ^ (ra & 7)) << 3)];
                    }
#pragma unroll
                    for (int j = 0; j < 2; ++j) {
                        int rb = wn * 32 + j * 16 + (lane & 15);
                        bfr[j] = *(const bf16x8_t*)&lB[rb * 64 + ((c8 ^ (rb & 7)) << 3)];
                    }
#pragma unroll
                    for (int i = 0; i < 4; ++i)
#pragma unroll
                        for (int j = 0; j < 2; ++j)
                            acc[i][j] = __builtin_amdgcn_mfma_f32_16x16x32_bf16(
                                af[i], bfr[j], acc[i][j], 0, 0, 0);
                }
                __syncthreads();
            }
            // epilogue: tile row rl = t-major (t*32+b) - m*128 ; out row = b*64+t
            const int lm = (lane >> 4) * 4, ln = lane & 15;
#pragma unroll
            for (int i = 0; i < 4; ++i) {
                int rl0 = wm * 64 + i * 16 + lm;
#pragma unroll
                for (int j = 0; j < 2; ++j) {
                    int gn = n * 128 + wn * 32 + j * 16 + ln;
                    float bb = bout[gn];
#pragma unroll
                    for (int r = 0; r < 4; ++r) {
                        int rl = rl0 + r;
                        int t = 4 * m + (rl >> 5), b = rl & 31;
                        outp[(size_t)(b * 64 + t) * 32000 + gn] = acc[i][j][r] + bb;
                    }
                }
            }
        }
        return;
    }

    // ================= scan roles =================
    unsigned short* Wl = (unsigned short*)smem;             // 96 KB f16 B-fragments
    u32x4_t* hstage4 = (u32x4_t*)(smem + 98304);            // 32 KB gather stage
    float* csm = (float*)(smem + 131072);                   // [2][3][32][34]
#define CSM(p, gt, b, c) csm[((((p)*3 + (gt)) * 32 + (b)) * 34) + (c)]
    const int gate = wave >> 1;         // 0=r 1=z 2=n (waves 0..5)
    const int mt = wave & 1;            // M-tile (batches 0-15 / 16-31)

    if (wg < NWG_L0) {
        // ================= L0 role: d-slice 32 =================
        const int d0 = wg * 32;
        for (int idx = tid; idx < 6144; idx += 512) {
            int ln = idx & 63, kk = (idx >> 6) & 15, nt = (idx >> 10) & 1, g_ = idx >> 11;
            int grow = g_ * 512 + d0 + nt * 16 + (ln & 15);
            int k = kk * 32 + ((ln >> 4) << 3);
            const float* src = Whh0 + (size_t)grow * 512 + k;
            f16x8_t v;
#pragma unroll
            for (int j = 0; j < 8; ++j) v[j] = (_Float16)src[j];
            *(f16x8_t*)&Wl[idx << 3] = v;
        }
        const int ub = tid >> 4, dpl = (tid & 15) * 2, ud = d0 + dpl;
        float h_lo = hinit[(size_t)ub * 512 + ud];
        float h_hi = hinit[(size_t)ub * 512 + ud + 1];
        const float br_lo = bhh0[ud],        br_hi = bhh0[ud + 1];
        const float bz_lo = bhh0[512 + ud],  bz_hi = bhh0[512 + ud + 1];
        const float bn_lo = bhh0[1024 + ud], bn_hi = bhh0[1024 + ud + 1];
        const int lenb = lengths[ub];
        {   // init publish h0 -> h0x[0]
            unsigned int hw = (unsigned int)f2h(h_lo) | ((unsigned int)f2h(h_hi) << 16);
            __hip_atomic_store(&h0x32[ub * 256 + (ud >> 1)], hw, __ATOMIC_RELAXED, AS_AGENT);
        }
        asm volatile("s_waitcnt vmcnt(0)" ::: "memory");
        __syncthreads();
        if (tid == 0) __hip_atomic_store(&flags[wg << 5], 1, __ATOMIC_RELAXED, AS_AGENT);
        // xW0 prefetch for t=0
        const float* xrow = xW0 + (size_t)(ub * 64) * 1536 + ud;
        float2 px_r = *(const float2*)(xrow);
        float2 px_z = *(const float2*)(xrow + 512);
        float2 px_n = *(const float2*)(xrow + 1024);

        for (int r = 0; r < 64; ++r) {
            if (wave == 0) {
                const int tgt = r + 1;
                for (;;) {
                    int v = 0x40000000;
                    if (lane < NWG_TOT)
                        v = __hip_atomic_load(&flags[lane << 5], __ATOMIC_RELAXED, AS_AGENT);
                    if (__all(v >= tgt)) break;
                    __builtin_amdgcn_s_sleep(1);
                }
            }
            __syncthreads();
            // gather h0x[r&1] -> stage
            {
                const char* srcb = (const char*)h0x + ((r & 1) << 15);
                u32x4_t q0, q1, q2, q3;
                asm volatile("global_load_dwordx4 %0, %1, off sc0 sc1"
                             : "=v"(q0) : "v"(srcb + ((size_t)tid << 4)) : "memory");
                asm volatile("global_load_dwordx4 %0, %1, off sc0 sc1"
                             : "=v"(q1) : "v"(srcb + ((size_t)(512 + tid) << 4)) : "memory");
                asm volatile("global_load_dwordx4 %0, %1, off sc0 sc1"
                             : "=v"(q2) : "v"(srcb + ((size_t)(1024 + tid) << 4)) : "memory");
                asm volatile("global_load_dwordx4 %0, %1, off sc0 sc1"
                             : "=v"(q3) : "v"(srcb + ((size_t)(1536 + tid) << 4)) : "memory");
                asm volatile("s_waitcnt vmcnt(0)" ::: "memory");
                int g0 = tid, g1 = 512 + tid, g2 = 1024 + tid, g3 = 1536 + tid;
                hstage4[g0 ^ ((g0 >> 6) & 7)] = q0;
                hstage4[g1 ^ ((g1 >> 6) & 7)] = q1;
                hstage4[g2 ^ ((g2 >> 6) & 7)] = q2;
                hstage4[g3 ^ ((g3 >> 6) & 7)] = q3;
            }
            __syncthreads();
            if (wave < 6) {
                const int brow = mt * 16 + (lane & 15);
                const int ko = lane >> 4;
                f32x4_t acc0 = (f32x4_t){0.f, 0.f, 0.f, 0.f};
                f32x4_t acc1 = (f32x4_t){0.f, 0.f, 0.f, 0.f};
#pragma unroll
                for (int kk = 0; kk < 16; ++kk) {
                    int gg = brow * 64 + kk * 4 + ko;
                    f16x8_t af = __builtin_bit_cast(f16x8_t, hstage4[gg ^ (brow & 7)]);
                    f16x8_t bf0 = *(const f16x8_t*)&Wl[(((gate * 2 + 0) * 16 + kk) * 64 + lane) << 3];
                    f16x8_t bf1 = *(const f16x8_t*)&Wl[(((gate * 2 + 1) * 16 + kk) * 64 + lane) << 3];
                    acc0 = __builtin_amdgcn_mfma_f32_16x16x32_f16(af, bf0, acc0, 0, 0, 0);
                    acc1 = __builtin_amdgcn_mfma_f32_16x16x32_f16(af, bf1, acc1, 0, 0, 0);
                }
                const int crow = mt * 16 + ((lane >> 4) << 2), ccol = lane & 15;
#pragma unroll
                for (int rr = 0; rr < 4; ++rr) {
                    CSM(0, gate, crow + rr, ccol) = acc0[rr];
                    CSM(0, gate, crow + rr, 16 + ccol) = acc1[rr];
                }
            }
            __syncthreads();
            // gate update
            unsigned int ow = 0u;
            if (r < lenb) {
                float hr_lo = CSM(0, 0, ub, dpl), hr_hi = CSM(0, 0, ub, dpl + 1);
                float hz_lo = CSM(0, 1, ub, dpl), hz_hi = CSM(0, 1, ub, dpl + 1);
                float hn_lo = CSM(0, 2, ub, dpl), hn_hi = CSM(0, 2, ub, dpl + 1);
                float r0 = sigmoidf_(px_r.x + hr_lo + br_lo);
                float r1 = sigmoidf_(px_r.y + hr_hi + br_hi);
                float u0 = sigmoidf_(px_z.x + hz_lo + bz_lo);
                float u1 = sigmoidf_(px_z.y + hz_hi + bz_hi);
                float n0 = tanhf(px_n.x + r0 * (hn_lo + bn_lo));
                float n1 = tanhf(px_n.y + r1 * (hn_hi + bn_hi));
                h_lo = (1.f - u0) * n0 + u0 * h_lo;
                h_hi = (1.f - u1) * n1 + u1 * h_hi;
                ow = (unsigned int)f2h(h_lo) | ((unsigned int)f2h(h_hi) << 16);
            }
            // publish h0_{t+1} and out0[t]
            {
                unsigned int hw = (unsigned int)f2h(h_lo) | ((unsigned int)f2h(h_hi) << 16);
                __hip_atomic_store(&h0x32[((r + 1) & 1) * 8192 + ub * 256 + (ud >> 1)],
                                   hw, __ATOMIC_RELAXED, AS_AGENT);
                __hip_atomic_store(&o0x32[(r & 1) * 8192 + ub * 256 + (ud >> 1)],
                                   ow, __ATOMIC_RELAXED, AS_AGENT);
            }
            asm volatile("s_waitcnt vmcnt(0)" ::: "memory");
            __syncthreads();
            if (tid == 0) __hip_atomic_store(&flags[wg << 5], r + 2, __ATOMIC_RELAXED, AS_AGENT);
            // off-chain: xW0 prefetch for t=r+1
            {
                int tn = r + 1 < 64 ? r + 1 : 63;
                const float* xp = xW0 + (size_t)(ub * 64 + tn) * 1536 + ud;
                px_r = *(const float2*)(xp);
                px_z = *(const float2*)(xp + 512);
                px_n = *(const float2*)(xp + 1024);
            }
        }
    } else {
        // ================= L1 role: d-slice 16, K=1024 =================
        const int lid = wg - NWG_L0;
        const int d0 = lid * 16;
        for (int idx = tid; idx < 6144; idx += 512) {
            int ln = idx & 63, kk = (idx >> 6) & 31, g_ = idx >> 11;
            int grow = g_ * 512 + d0 + (ln & 15);
            int k = (kk & 15) * 32 + ((ln >> 4) << 3);
            const float* src = (kk < 16 ? Whh1 : Wih1) + (size_t)grow * 512 + k;
            f16x8_t v;
#pragma unroll
            for (int j = 0; j < 8; ++j) v[j] = (_Float16)src[j];
            *(f16x8_t*)&Wl[idx << 3] = v;
        }
        const bool upd = (tid < 256);
        const int ub = tid >> 3, dpl = (tid & 7) * 2, ud = d0 + dpl;
        float h_lo = 0.f, h_hi = 0.f;
        float br_lo = 0.f, br_hi = 0.f, bz_lo = 0.f, bz_hi = 0.f;
        float bxn_lo = 0.f, bxn_hi = 0.f, bhn_lo = 0.f, bhn_hi = 0.f;
        int lenb = 0;
        if (upd) {
            h_lo = hinit[16384 + (size_t)ub * 512 + ud];
            h_hi = hinit[16384 + (size_t)ub * 512 + ud + 1];
            br_lo = bih1[ud] + bhh1[ud];
            br_hi = bih1[ud + 1] + bhh1[ud + 1];
            bz_lo = bih1[512 + ud] + bhh1[512 + ud];
            bz_hi = bih1[512 + ud + 1] + bhh1[512 + ud + 1];
            bxn_lo = bih1[1024 + ud];   bxn_hi = bih1[1024 + ud + 1];
            bhn_lo = bhh1[1024 + ud];   bhn_hi = bhh1[1024 + ud + 1];
            lenb = lengths[ub];
            // init publish h1 -> h1x[1] (round 1 reads parity 1)
            unsigned int hw = (unsigned int)f2h(h_lo) | ((unsigned int)f2h(h_hi) << 16);
            __hip_atomic_store(&h1x32[8192 + ub * 256 + (ud >> 1)], hw, __ATOMIC_RELAXED, AS_AGENT);
        }
        asm volatile("s_waitcnt vmcnt(0)" ::: "memory");
        __syncthreads();
        if (tid == 0) __hip_atomic_store(&flags[wg << 5], 2, __ATOMIC_RELAXED, AS_AGENT);

        for (int r = 1; r <= 64; ++r) {
            const int t1 = r - 1;
            if (wave == 0) {
                const int tgt = r + 1;
                for (;;) {
                    int v = 0x40000000;
                    if (lane < NWG_TOT)
                        v = __hip_atomic_load(&flags[lane << 5], __ATOMIC_RELAXED, AS_AGENT);
                    if (__all(v >= tgt)) break;
                    __builtin_amdgcn_s_sleep(1);
                }
            }
            __syncthreads();
            // gather: h1 first (4 loads), then out0 (4 loads); counted waits
            u32x4_t a0, a1, a2, a3, b0, b1, b2, b3;
            {
                const char* sh = (const char*)h1x + ((r & 1) << 15);
                const char* so = (const char*)o0x + (((r + 1) & 1) << 15);
                asm volatile("global_load_dwordx4 %0, %1, off sc0 sc1"
                             : "=v"(a0) : "v"(sh + ((size_t)tid << 4)) : "memory");
                asm volatile("global_load_dwordx4 %0, %1, off sc0 sc1"
                             : "=v"(a1) : "v"(sh + ((size_t)(512 + tid) << 4)) : "memory");
                asm volatile("global_load_dwordx4 %0, %1, off sc0 sc1"
                             : "=v"(a2) : "v"(sh + ((size_t)(1024 + tid) << 4)) : "memory");
                asm volatile("global_load_dwordx4 %0, %1, off sc0 sc1"
                             : "=v"(a3) : "v"(sh + ((size_t)(1536 + tid) << 4)) : "memory");
                asm volatile("global_load_dwordx4 %0, %1, off sc0 sc1"
                             : "=v"(b0) : "v"(so + ((size_t)tid << 4)) : "memory");
                asm volatile("global_load_dwordx4 %0, %1, off sc0 sc1"
                             : "=v"(b1) : "v"(so + ((size_t)(512 + tid) << 4)) : "memory");
                asm volatile("global_load_dwordx4 %0, %1, off sc0 sc1"
                             : "=v"(b2) : "v"(so + ((size_t)(1024 + tid) << 4)) : "memory");
                asm volatile("global_load_dwordx4 %0, %1, off sc0 sc1"
                             : "=v"(b3) : "v"(so + ((size_t)(1536 + tid) << 4)) : "memory");
                asm volatile("s_waitcnt vmcnt(4)" ::: "memory");  // h1 done
                int g0 = tid, g1 = 512 + tid, g2 = 1024 + tid, g3 = 1536 + tid;
                hstage4[g0 ^ ((g0 >> 6) & 7)] = a0;
                hstage4[g1 ^ ((g1 >> 6) & 7)] = a1;
                hstage4[g2 ^ ((g2 >> 6) & 7)] = a2;
                hstage4[g3 ^ ((g3 >> 6) & 7)] = a3;
            }
            __syncthreads();
            // pass 0: acc_h = h1 @ Whh1^T (one 16x16 tile per wave)
            f32x4_t acc_h = (f32x4_t){0.f, 0.f, 0.f, 0.f};
            const int brow = mt * 16 + (lane & 15);
            const int ko = lane >> 4;
            if (wave < 6) {
#pragma unroll
                for (int kk = 0; kk < 16; ++kk) {
                    int gg = brow * 64 + kk * 4 + ko;
                    f16x8_t af = __builtin_bit_cast(f16x8_t, hstage4[gg ^ (brow & 7)]);
                    f16x8_t bf = *(const f16x8_t*)&Wl[(((gate * 32 + kk) * 64 + lane)) << 3];
                    acc_h = __builtin_amdgcn_mfma_f32_16x16x32_f16(af, bf, acc_h, 0, 0, 0);
                }
            }
            __syncthreads();  // all reads of h1 stage done
            {
                asm volatile("s_waitcnt vmcnt(0)" ::: "memory");  // out0 done
                int g0 = tid, g1 = 512 + tid, g2 = 1024 + tid, g3 = 1536 + tid;
                hstage4[g0 ^ ((g0 >> 6) & 7)] = b0;
                hstage4[g1 ^ ((g1 >> 6) & 7)] = b1;
                hstage4[g2 ^ ((g2 >> 6) & 7)] = b2;
                hstage4[g3 ^ ((g3 >> 6) & 7)] = b3;
            }
            __syncthreads();
            // pass 1: acc_x = out0 @ Wih1^T
            if (wave < 6) {
                f32x4_t acc_x = (f32x4_t){0.f, 0.f, 0.f, 0.f};
#pragma unroll
                for (int kk = 0; kk < 16; ++kk) {
                    int gg = brow * 64 + kk * 4 + ko;
                    f16x8_t af = __builtin_bit_cast(f16x8_t, hstage4[gg ^ (brow & 7)]);
                    f16x8_t bf = *(const f16x8_t*)&Wl[(((gate * 32 + 16 + kk) * 64 + lane)) << 3];
                    acc_x = __builtin_amdgcn_mfma_f32_16x16x32_f16(af, bf, acc_x, 0, 0, 0);
                }
                const int crow = mt * 16 + ((lane >> 4) << 2), ccol = lane & 15;
#pragma unroll
                for (int rr = 0; rr < 4; ++rr) {
                    CSM(0, gate, crow + rr, ccol) = acc_h[rr];
                    CSM(1, gate, crow + rr, ccol) = acc_x[rr];
                }
            }
            __syncthreads();
            // gate update (n-gate: x-part and h-part kept separate)
            unsigned int ow = 0u;
            if (upd) {
                if (t1 < lenb) {
                    float hr_lo = CSM(0, 0, ub, dpl), hr_hi = CSM(0, 0, ub, dpl + 1);
                    float hz_lo = CSM(0, 1, ub, dpl), hz_hi = CSM(0, 1, ub, dpl + 1);
                    float hn_lo = CSM(0, 2, ub, dpl), hn_hi = CSM(0, 2, ub, dpl + 1);
                    float xr_lo = CSM(1, 0, ub, dpl), xr_hi = CSM(1, 0, ub, dpl + 1);
                    float xz_lo = CSM(1, 1, ub, dpl), xz_hi = CSM(1, 1, ub, dpl + 1);
                    float xn_lo = CSM(1, 2, ub, dpl), xn_hi = CSM(1, 2, ub, dpl + 1);
                    float r0 = sigmoidf_(xr_lo + hr_lo + br_lo);
                    float r1 = sigmoidf_(xr_hi + hr_hi + br_hi);
                    float u0 = sigmoidf_(xz_lo + hz_lo + bz_lo);
                    float u1 = sigmoidf_(xz_hi + hz_hi + bz_hi);
                    float n0 = tanhf(xn_lo + bxn_lo + r0 * (hn_lo + bhn_lo));
                    float n1 = tanhf(xn_hi + bxn_hi + r1 * (hn_hi + bhn_hi));
                    h_lo = (1.f - u0) * n0 + u0 * h_lo;
                    h_hi = (1.f - u1) * n1 + u1 * h_hi;
                    ow = (unsigned int)f2bf(h_lo) | ((unsigned int)f2bf(h_hi) << 16);
                }
                if (r < 64) {
                    unsigned int hw = (unsigned int)f2h(h_lo) | ((unsigned int)f2h(h_hi) << 16);
                    __hip_atomic_store(&h1x32[((r + 1) & 1) * 8192 + ub * 256 + (ud >> 1)],
                                       hw, __ATOMIC_RELAXED, AS_AGENT);
                }
                // out1 publish: t-major bf16, bypass, pre-drain (GEMM role reads it)
                __hip_atomic_store(&o1x32[(size_t)(t1 * 32 + ub) * 256 + (ud >> 1)],
                                   ow, __ATOMIC_RELAXED, AS_AGENT);
            }
            asm volatile("s_waitcnt vmcnt(0)" ::: "memory");
            __syncthreads();
            if (tid == 0)
                __hip_atomic_store(&flags[wg << 5], r + 2, __ATOMIC_RELAXED, AS_AGENT);
        }
    }
#undef CSM
}

extern "C" void kernel_launch(void* const* d_in, const int* in_sizes, int n_in,
                              void* d_out, int out_size, void* d_ws, size_t ws_size,
                              hipStream_t stream) {
    const int*   tok    = (const int*)d_in[0];
    const int*   lens   = (const int*)d_in[1];
    const float* noise  = (const float*)d_in[2];
    const float* table  = (const float*)d_in[3];
    const float* Wm     = (const float*)d_in[4];
    const float* bm_    = (const float*)d_in[5];
    const float* Wv     = (const float*)d_in[6];
    const float* bv_    = (const float*)d_in[7];
    const float* Wl2r   = (const float*)d_in[8];
    const float* bl2r   = (const float*)d_in[9];
    const float* Wih0   = (const float*)d_in[10];
    const float* Whh0   = (const float*)d_in[11];
    const float* bih0   = (const float*)d_in[12];
    const float* bhh0   = (const float*)d_in[13];
    const float* Wih1   = (const float*)d_in[14];
    const float* Whh1   = (const float*)d_in[15];
    const float* bih1   = (const float*)d_in[16];
    const float* bhh1   = (const float*)d_in[17];
    const float* Wout   = (const float*)d_in[18];
    const float* bout   = (const float*)d_in[19];
    const float* lW1 = (const float*)d_in[20]; const float* lb1 = (const float*)d_in[21];
    const float* lW2 = (const float*)d_in[22]; const float* lb2 = (const float*)d_in[23];
    const float* lW3 = (const float*)d_in[24]; const float* lb3 = (const float*)d_in[25];
    const float* sW1 = (const float*)d_in[26]; const float* sb1 = (const float*)d_in[27];
    const float* sW2 = (const float*)d_in[28]; const float* sb2 = (const float*)d_in[29];
    const float* sW3 = (const float*)d_in[30]; const float* sb3 = (const float*)d_in[31];

    float* out    = (float*)d_out;           // (B,S,V) = 2048 x 32000
    float* o_mean = out + 65536000;
    float* o_std  = o_mean + 2048;
    float* o_z    = o_std + 2048;
    float* o_logp = o_z + 4096;
    float* o_sas  = o_logp + 32;

    char* ws = (char*)d_ws;
    unsigned short* Woutb = (unsigned short*)ws;  ws += 32768000;  // 32000x512 bf16
    unsigned short* Wih0b = (unsigned short*)ws;  ws += 393216;    // 1536x128 bf16
    unsigned short* embb  = (unsigned short*)ws;  ws += 524288;    // 2048x128 bf16
    float*          vf    = (float*)ws;           ws += 16384;     // 32x128
    float*          state = (float*)ws;           ws += 131072;    // 2x32x512
    float*          xW    = (float*)ws;           ws += 12582912;  // 2048x1536 f32 (layer 0)
    unsigned short* out1x = (unsigned short*)ws;  ws += 2097152;   // 2048x512 bf16 t-major
    unsigned short* h0x   = (unsigned short*)ws;  ws += 131072;    // 2x32x512 f16
    unsigned short* h1x   = (unsigned short*)ws;  ws += 131072;
    unsigned short* o0x   = (unsigned short*)ws;  ws += 131072;
    int*            flgp  = (int*)ws;             ws += 8192;      // 48 flags x 128B

    // weight preprocessing (input-independent)
    cvt_bf16_kernel<<<dim3(4096), dim3(256), 0, stream>>>(Wout, Woutb, 16384000 / 4);
    cvt_bf16_kernel<<<dim3(192),  dim3(256), 0, stream>>>(Wih0, Wih0b, 196608 / 4);
    hipMemsetAsync(flgp, 0, 8192, stream);

    // encoder path
    embed_kernel<<<dim3(32), dim3(128), 0, stream>>>(tok, table, embb, vf);
    encoder_kernel<<<dim3(32), dim3(256), 0, stream>>>(vf, Wm, bm_, Wv, bv_, noise, Wl2r, bl2r,
                                                       lW1, lb1, lW2, lb2, lW3, lb3,
                                                       sW1, sb1, sW2, sb2, sW3, sb3,
                                                       o_mean, o_std, o_z, o_logp, o_sas, state);

    // layer-0 xW GEMM (K=128), then persistent 3-role kernel (scan + shadow GEMM)
    gemm_bt_kernel<<<dim3(12, 16), dim3(256), 0, stream>>>(embb, Wih0b, bih0, xW, 2048, 1536, 128);
    gru_fused_kernel<<<dim3(NWG_ALL), dim3(512), 0, stream>>>(
        xW, Whh0, bhh0, Whh1, Wih1, bih1, bhh1, state, lens,
        h0x, h1x, o0x, out1x, Woutb, bout, out, flgp);
}